// Round 10
// baseline (908.828 us; speedup 1.0000x reference)
//
#include <hip/hip_runtime.h>
#include <hip/hip_bf16.h>

// ---------------------------------------------------------------------------
// CapsuleNetwork: embedding -> 2-layer BiLSTM -> attn pooling -> routing
// Round 9: (1) scan exchange = single-roundtrip tagged u64 payload
//              (tag<<32|f32 h), no flags/poll-barrier; R7's conflict-free
//              interleaved-k phase1. (2) mgemm reg-prefetch double-buffer.
// B=128 T=64 E=300 H=256 DA=128 R=8 SC=32 AT=16
// ---------------------------------------------------------------------------

typedef __attribute__((ext_vector_type(8))) short bf16x8;
typedef __attribute__((ext_vector_type(4))) float f32x4;

__device__ __forceinline__ float sigf(float x) { return 1.0f / (1.0f + __expf(-x)); }
__device__ __forceinline__ float tanhf_fast(float x) { return 1.0f - 2.0f / (__expf(2.0f * x) + 1.0f); }

#define DPPF(v, ctrl) __int_as_float(__builtin_amdgcn_update_dpp(0, __float_as_int(v), ctrl, 0xF, 0xF, true))

// ---------------- transpose w_hh [1024][256] -> Wt [256][1024] -------------
__global__ void k_transpose(const float* __restrict__ w0, const float* __restrict__ w1,
                            const float* __restrict__ w2, const float* __restrict__ w3,
                            float* __restrict__ wt)
{
    __shared__ float tile[32][33];
    const float* W = (blockIdx.z == 0) ? w0 : (blockIdx.z == 1) ? w1 : (blockIdx.z == 2) ? w2 : w3;
    float* Wt = wt + (size_t)blockIdx.z * 256 * 1024;
    const int j0 = blockIdx.x * 32, k0 = blockIdx.y * 32;
    const int tx = threadIdx.x, ty = threadIdx.y;  // (32,8)
    #pragma unroll
    for (int i = 0; i < 32; i += 8)
        tile[ty + i][tx] = W[(size_t)(j0 + ty + i) * 256 + (k0 + tx)];
    __syncthreads();
    #pragma unroll
    for (int i = 0; i < 32; i += 8)
        Wt[(size_t)(k0 + ty + i) * 1024 + (j0 + tx)] = tile[tx][ty + i];
}

// ---------------- zero words -----------------------------------------------
__global__ void k_zero(int* __restrict__ p, int n)
{
    const int i = blockIdx.x * blockDim.x + threadIdx.x;
    if (i < n) p[i] = 0;
}

// ---------------- fp32 -> (hi,lo) bf16 split, optional gather + K-pad ------
__global__ void k_split(const float* __restrict__ src, const int* __restrict__ tokens,
                        int Kin, int Kp, unsigned short* __restrict__ hi,
                        unsigned short* __restrict__ lo)
{
    const int i4 = (blockIdx.x * 256 + threadIdx.x) * 4;
    const int r = i4 / Kp;
    const int k = i4 - r * Kp;
    const float* srow;
    if (tokens) {
        const int t = r >> 7, b = r & 127;
        srow = src + (size_t)tokens[b * 64 + t] * Kin;
    } else {
        srow = src + (size_t)r * Kin;
    }
    float e[4];
    if (k + 4 <= Kin) {
        const float4 v = *(const float4*)(srow + k);
        e[0] = v.x; e[1] = v.y; e[2] = v.z; e[3] = v.w;
    } else {
        #pragma unroll
        for (int j = 0; j < 4; ++j) e[j] = (k + j < Kin) ? srow[k + j] : 0.0f;
    }
    ushort4 hv, lv;
    #pragma unroll
    for (int j = 0; j < 4; ++j) {
        __hip_bfloat16 bh = __float2bfloat16(e[j]);
        const float fh = __bfloat162float(bh);
        __hip_bfloat16 bl = __float2bfloat16(e[j] - fh);
        ((unsigned short*)&hv)[j] = *(unsigned short*)&bh;
        ((unsigned short*)&lv)[j] = *(unsigned short*)&bl;
    }
    *(ushort4*)&hi[(size_t)r * Kp + k] = hv;
    *(ushort4*)&lo[(size_t)r * Kp + k] = lv;
}

// ---------------- bf16x3 MFMA GEMM, reg-prefetch double-buffered -----------
// C[m][n] = sum_k A[m,k]*W[n,k] + bias[n]; 3 MFMAs/frag (hh + hl + lh).
// Tile 128x128, 4 waves (2x2 of 64x64), 4x4 frags of 16x16x32, LDS stride 40.
__global__ __launch_bounds__(256) void k_mgemm(
    const unsigned short* __restrict__ Ahi, const unsigned short* __restrict__ Alo,
    const unsigned short* __restrict__ Whi, const unsigned short* __restrict__ Wlo,
    const float* __restrict__ bias0, const float* __restrict__ bias1, int nsplit,
    float* __restrict__ C, int ldc, int Kp)
{
    __shared__ unsigned short lAh[128 * 40];
    __shared__ unsigned short lAl[128 * 40];
    __shared__ unsigned short lBh[128 * 40];
    __shared__ unsigned short lBl[128 * 40];

    const int tid = threadIdx.x;
    const int m0 = blockIdx.x * 128;
    const int n0 = blockIdx.y * 128;
    const int w  = tid >> 6, l = tid & 63;
    const int wm = (w >> 1) * 64, wn = (w & 1) * 64;
    const int lr = l & 15, lk = (l >> 4) * 8;

    // staging coords (2 chunks per thread)
    int srow[2], sk8[2];
    #pragma unroll
    for (int p = 0; p < 2; ++p) {
        const int chunk = tid + p * 256;
        srow[p] = chunk >> 2;
        sk8[p]  = (chunk & 3) * 8;
    }

    f32x4 acc[4][4];
    #pragma unroll
    for (int i = 0; i < 4; ++i)
        #pragma unroll
        for (int j = 0; j < 4; ++j)
            acc[i][j] = (f32x4){0.f, 0.f, 0.f, 0.f};

    bf16x8 rah[2], ral[2], rbh[2], rbl[2];
    // prologue: prefetch tile 0
    #pragma unroll
    for (int p = 0; p < 2; ++p) {
        const size_t ga = (size_t)(m0 + srow[p]) * Kp + sk8[p];
        const size_t gb = (size_t)(n0 + srow[p]) * Kp + sk8[p];
        rah[p] = *(const bf16x8*)&Ahi[ga];
        ral[p] = *(const bf16x8*)&Alo[ga];
        rbh[p] = *(const bf16x8*)&Whi[gb];
        rbl[p] = *(const bf16x8*)&Wlo[gb];
    }

    for (int kt = 0; kt < Kp; kt += 32) {
        // ---- write prefetched regs to LDS ----
        #pragma unroll
        for (int p = 0; p < 2; ++p) {
            const int la = srow[p] * 40 + sk8[p];
            *(bf16x8*)&lAh[la] = rah[p];
            *(bf16x8*)&lAl[la] = ral[p];
            *(bf16x8*)&lBh[la] = rbh[p];
            *(bf16x8*)&lBl[la] = rbl[p];
        }
        __syncthreads();
        // ---- prefetch next tile (hidden under MFMAs) ----
        if (kt + 32 < Kp) {
            #pragma unroll
            for (int p = 0; p < 2; ++p) {
                const size_t ga = (size_t)(m0 + srow[p]) * Kp + kt + 32 + sk8[p];
                const size_t gb = (size_t)(n0 + srow[p]) * Kp + kt + 32 + sk8[p];
                rah[p] = *(const bf16x8*)&Ahi[ga];
                ral[p] = *(const bf16x8*)&Alo[ga];
                rbh[p] = *(const bf16x8*)&Whi[gb];
                rbl[p] = *(const bf16x8*)&Wlo[gb];
            }
        }
        // ---- fragments + 48 MFMAs ----
        bf16x8 ah[4], al[4], bh[4], bl[4];
        #pragma unroll
        for (int f = 0; f < 4; ++f) {
            const int ra = (wm + f * 16 + lr) * 40 + lk;
            const int rb = (wn + f * 16 + lr) * 40 + lk;
            ah[f] = *(const bf16x8*)&lAh[ra];
            al[f] = *(const bf16x8*)&lAl[ra];
            bh[f] = *(const bf16x8*)&lBh[rb];
            bl[f] = *(const bf16x8*)&lBl[rb];
        }
        #pragma unroll
        for (int fm = 0; fm < 4; ++fm)
            #pragma unroll
            for (int fn = 0; fn < 4; ++fn) {
                acc[fm][fn] = __builtin_amdgcn_mfma_f32_16x16x32_bf16(ah[fm], bh[fn], acc[fm][fn], 0, 0, 0);
                acc[fm][fn] = __builtin_amdgcn_mfma_f32_16x16x32_bf16(ah[fm], bl[fn], acc[fm][fn], 0, 0, 0);
                acc[fm][fn] = __builtin_amdgcn_mfma_f32_16x16x32_bf16(al[fm], bh[fn], acc[fm][fn], 0, 0, 0);
            }
        __syncthreads();
    }
    // ---- epilogue ----
    #pragma unroll
    for (int fm = 0; fm < 4; ++fm)
        #pragma unroll
        for (int fn = 0; fn < 4; ++fn) {
            const int col = n0 + wn + fn * 16 + lr;
            const float bv = (col < nsplit) ? (bias0 ? bias0[col] : 0.f)
                                            : (bias1 ? bias1[col - nsplit] : 0.f);
            #pragma unroll
            for (int j = 0; j < 4; ++j) {
                const int row = m0 + wm + fm * 16 + (l >> 4) * 4 + j;
                C[(size_t)row * ldc + col] = acc[fm][fn][j] + bv;
            }
        }
}

// ---------------- fp32 GEMM (R6) — used for hbar & votes only --------------
__global__ __launch_bounds__(256) void k_gemm(
    const float* __restrict__ A, int lda, const int* __restrict__ tokens,
    const float* __restrict__ W0, const float* __restrict__ W1, int nsplit, int ldw,
    const float* __restrict__ bias0, const float* __restrict__ bias1,
    float* __restrict__ C, int ldc, int K, int transb, int act_tanh,
    long long sA, long long sW, long long sC)
{
    __shared__ float As[32][128];
    __shared__ float Ws[32][128];
    A  += (size_t)blockIdx.z * (size_t)sA;
    W0 += (size_t)blockIdx.z * (size_t)sW;
    C  += (size_t)blockIdx.z * (size_t)sC;
    const int tid = threadIdx.x;
    const int m0 = blockIdx.x * 128;
    const int n0 = blockIdx.y * 128;

    const int srow = tid >> 1;
    const int kh   = (tid & 1) * 16;
    const int am = m0 + srow;
    const float* arow;
    if (tokens) {
        const int t = am >> 7, b = am & 127;
        arow = A + (size_t)tokens[b * 64 + t] * lda;
    } else {
        arow = A + (size_t)am * lda;
    }
    const int wn = n0 + srow;
    const float* wrow = (wn < nsplit) ? (W0 + (size_t)wn * ldw)
                                      : (W1 + (size_t)(wn - nsplit) * ldw);
    const int kw = tid >> 3;
    const int n8 = (tid & 7) * 16;

    const int tm4 = (tid & 15) * 4;
    const int tn4 = (tid >> 4) * 4;
    float acc[8][8] = {};
    float4 ra[4], rw[4];

    const int nt = (K + 31) / 32;

    #pragma unroll
    for (int j = 0; j < 4; ++j) {
        const int k = kh + j * 4;
        if (k + 3 < K) ra[j] = *(const float4*)(arow + k);
        else {
            float t0 = (k + 0 < K) ? arow[k + 0] : 0.f;
            float t1 = (k + 1 < K) ? arow[k + 1] : 0.f;
            float t2 = (k + 2 < K) ? arow[k + 2] : 0.f;
            float t3 = (k + 3 < K) ? arow[k + 3] : 0.f;
            ra[j] = make_float4(t0, t1, t2, t3);
        }
    }
    if (transb) {
        #pragma unroll
        for (int j = 0; j < 4; ++j) {
            const int k = kh + j * 4;
            if (k + 3 < K) rw[j] = *(const float4*)(wrow + k);
            else {
                float t0 = (k + 0 < K) ? wrow[k + 0] : 0.f;
                float t1 = (k + 1 < K) ? wrow[k + 1] : 0.f;
                float t2 = (k + 2 < K) ? wrow[k + 2] : 0.f;
                float t3 = (k + 3 < K) ? wrow[k + 3] : 0.f;
                rw[j] = make_float4(t0, t1, t2, t3);
            }
        }
    } else {
        const float* src = (kw < K) ? (W0 + (size_t)kw * ldw + n0 + n8) : W0;
        #pragma unroll
        for (int j = 0; j < 4; ++j)
            rw[j] = (kw < K) ? *(const float4*)(src + j * 4) : make_float4(0, 0, 0, 0);
    }

    for (int tile = 0; tile < nt; ++tile) {
        #pragma unroll
        for (int j = 0; j < 4; ++j) {
            As[kh + j * 4 + 0][srow] = ra[j].x;
            As[kh + j * 4 + 1][srow] = ra[j].y;
            As[kh + j * 4 + 2][srow] = ra[j].z;
            As[kh + j * 4 + 3][srow] = ra[j].w;
        }
        if (transb) {
            #pragma unroll
            for (int j = 0; j < 4; ++j) {
                Ws[kh + j * 4 + 0][srow] = rw[j].x;
                Ws[kh + j * 4 + 1][srow] = rw[j].y;
                Ws[kh + j * 4 + 2][srow] = rw[j].z;
                Ws[kh + j * 4 + 3][srow] = rw[j].w;
            }
        } else {
            #pragma unroll
            for (int j = 0; j < 4; ++j)
                *(float4*)&Ws[kw][n8 + j * 4] = rw[j];
        }
        __syncthreads();
        if (tile + 1 < nt) {
            const int kb = (tile + 1) * 32;
            #pragma unroll
            for (int j = 0; j < 4; ++j) {
                const int k = kb + kh + j * 4;
                if (k + 3 < K) ra[j] = *(const float4*)(arow + k);
                else {
                    float t0 = (k + 0 < K) ? arow[k + 0] : 0.f;
                    float t1 = (k + 1 < K) ? arow[k + 1] : 0.f;
                    float t2 = (k + 2 < K) ? arow[k + 2] : 0.f;
                    float t3 = (k + 3 < K) ? arow[k + 3] : 0.f;
                    ra[j] = make_float4(t0, t1, t2, t3);
                }
            }
            if (transb) {
                #pragma unroll
                for (int j = 0; j < 4; ++j) {
                    const int k = kb + kh + j * 4;
                    if (k + 3 < K) rw[j] = *(const float4*)(wrow + k);
                    else {
                        float t0 = (k + 0 < K) ? wrow[k + 0] : 0.f;
                        float t1 = (k + 1 < K) ? wrow[k + 1] : 0.f;
                        float t2 = (k + 2 < K) ? wrow[k + 2] : 0.f;
                        float t3 = (k + 3 < K) ? wrow[k + 3] : 0.f;
                        rw[j] = make_float4(t0, t1, t2, t3);
                    }
                }
            } else {
                const int k = kb + kw;
                const float* src = (k < K) ? (W0 + (size_t)k * ldw + n0 + n8) : W0;
                #pragma unroll
                for (int j = 0; j < 4; ++j)
                    rw[j] = (k < K) ? *(const float4*)(src + j * 4) : make_float4(0, 0, 0, 0);
            }
        }
        #pragma unroll 8
        for (int kk = 0; kk < 32; ++kk) {
            const float4 a0 = *(const float4*)&As[kk][tm4];
            const float4 a1 = *(const float4*)&As[kk][tm4 + 64];
            const float4 b0 = *(const float4*)&Ws[kk][tn4];
            const float4 b1 = *(const float4*)&Ws[kk][tn4 + 64];
            const float av[8] = {a0.x, a0.y, a0.z, a0.w, a1.x, a1.y, a1.z, a1.w};
            const float bv[8] = {b0.x, b0.y, b0.z, b0.w, b1.x, b1.y, b1.z, b1.w};
            #pragma unroll
            for (int i = 0; i < 8; ++i)
                #pragma unroll
                for (int j = 0; j < 8; ++j)
                    acc[i][j] += av[i] * bv[j];
        }
        __syncthreads();
    }
    const int half = (n0 >= nsplit) ? 1 : 0;
    const float* bp = half ? bias1 : bias0;
    const int nl = n0 - (half ? nsplit : 0);
    #pragma unroll
    for (int i = 0; i < 8; ++i) {
        const int row = m0 + tm4 + (i >> 2) * 64 + (i & 3);
        #pragma unroll
        for (int jh = 0; jh < 2; ++jh) {
            float v[4];
            #pragma unroll
            for (int j = 0; j < 4; ++j) {
                float x = acc[i][jh * 4 + j];
                if (bp) x += bp[nl + tn4 + jh * 64 + j];
                if (act_tanh) x = tanhf_fast(x);
                v[j] = x;
            }
            *(float4*)(C + (size_t)row * ldc + n0 + tn4 + jh * 64) =
                make_float4(v[0], v[1], v[2], v[3]);
        }
    }
}

// ---------------- BiLSTM scan: tagged single-roundtrip exchange ------------
// 512 blocks x 512 thr (2/CU). bx = dir*256 + s*32 + q. W[32][2] in regs,
// R7 interleaved-k phase1 (k = i*8+ks, linear hbuf [dim][4b], 0 conflicts).
// Exchange: hxt u64 = (tag<<32)|f32(h); writer = ONE relaxed agent atomic
// store (tag+payload atomic together -> no flag, no drain, no poll barrier);
// reader retry-loads its 2 elements until tag==tag_base+tt. Parity-2 buffer;
// per-scan tag ranges; hxt zeroed each launch (replay-safe).
__global__ __launch_bounds__(512, 4) void k_scan6(
    const float* __restrict__ Zin, const float* __restrict__ WtF,
    const float* __restrict__ WtB, float* __restrict__ outbuf,
    int bt_layout, unsigned long long* __restrict__ hxt, int tag_base, int bx_base)
{
    __shared__ __align__(16) float hbuf[1024];   // [dim][4b] linear
    __shared__ float zbuf[512];                  // [4b][128 local cols]

    const int bx  = blockIdx.x + bx_base;
    const int dir = bx >> 8;
    const int s   = (bx & 255) >> 5;
    const int q   = bx & 31;
    const int tid = threadIdx.x;
    const int cg  = tid >> 3;          // 0..63 col group (2 cols)
    const int ks  = tid & 7;           // 0..7  k lane
    const float* __restrict__ Wt = dir ? WtB : WtF;

    const int gate = cg >> 4;          // 0..3
    const int wg   = cg & 15;          // 0..15
    const int colbase = gate * 256 + s * 32 + wg * 2;
    // W rows k = i*8+ks, 2 cols each (interleaved-k to match phase1)
    float W[32][2];
    {
        const float* wp = Wt + (size_t)ks * 1024 + colbase;
        #pragma unroll
        for (int i = 0; i < 32; ++i) {
            const float2 w2 = *(const float2*)(wp + (size_t)i * 8192);
            W[i][0] = w2.x; W[i][1] = w2.y;
        }
    }

    const int pb  = tid >> 5;          // batch 0..3   (phase2, tid<128)
    const int pd  = tid & 31;          // local dim
    const int dim = s * 32 + pd;
    const int gb  = q * 4 + pb;
    float c_state = 0.0f;

    for (int tt = 0; tt < 64; ++tt) {
        const int t = dir ? (63 - tt) : tt;
        float z0 = 0.f, z1 = 0.f, z2 = 0.f, z3 = 0.f;
        if (tid < 128) {
            const float* zr = Zin + (size_t)(t * 128 + gb) * 2048 + dir * 1024 + dim;
            z0 = zr[0]; z1 = zr[256]; z2 = zr[512]; z3 = zr[768];
        }
        if (tt > 0) {
            // ---- tagged staging: retry until tag matches ----
            const unsigned long long expt = (unsigned long long)(tag_base + tt);
            unsigned long long* hsrc =
                hxt + ((((size_t)((tt - 1) & 1)) * 2 + dir) * 32 + q) * 1024;
            unsigned long long a0 = __hip_atomic_load(&hsrc[2 * tid], __ATOMIC_RELAXED,
                                                      __HIP_MEMORY_SCOPE_AGENT);
            while ((a0 >> 32) != expt) {
                __builtin_amdgcn_s_sleep(1);
                a0 = __hip_atomic_load(&hsrc[2 * tid], __ATOMIC_RELAXED,
                                       __HIP_MEMORY_SCOPE_AGENT);
            }
            unsigned long long a1 = __hip_atomic_load(&hsrc[2 * tid + 1], __ATOMIC_RELAXED,
                                                      __HIP_MEMORY_SCOPE_AGENT);
            while ((a1 >> 32) != expt) {
                __builtin_amdgcn_s_sleep(1);
                a1 = __hip_atomic_load(&hsrc[2 * tid + 1], __ATOMIC_RELAXED,
                                       __HIP_MEMORY_SCOPE_AGENT);
            }
            float2 hv;
            hv.x = __uint_as_float((unsigned)a0);
            hv.y = __uint_as_float((unsigned)a1);
            *(float2*)&hbuf[2 * tid] = hv;
            __syncthreads();
            // ---- phase 1: interleaved-k partial dot (conflict-free) ----
            float acc[4][2] = {};
            #pragma unroll
            for (int i = 0; i < 32; ++i) {
                const int k = i * 8 + ks;
                const float4 h4 = *(const float4*)&hbuf[k << 2];
                acc[0][0] += h4.x * W[i][0]; acc[0][1] += h4.x * W[i][1];
                acc[1][0] += h4.y * W[i][0]; acc[1][1] += h4.y * W[i][1];
                acc[2][0] += h4.z * W[i][0]; acc[2][1] += h4.z * W[i][1];
                acc[3][0] += h4.w * W[i][0]; acc[3][1] += h4.w * W[i][1];
            }
            // ---- DPP butterfly all-reduce over the 8 ks-lanes ----
            #pragma unroll
            for (int b = 0; b < 4; ++b)
                #pragma unroll
                for (int c = 0; c < 2; ++c) {
                    float v = acc[b][c];
                    v += DPPF(v, 0xB1);                  // xor 1
                    v += DPPF(v, 0x4E);                  // xor 2
                    v += DPPF(DPPF(v, 0x141), 0x1B);     // xor 4
                    acc[b][c] = v;
                }
            #pragma unroll
            for (int a = 0; a < 8; ++a)
                if (ks == a)
                    zbuf[(a >> 1) * 128 + gate * 32 + wg * 2 + (a & 1)] = acc[a >> 1][a & 1];
            __syncthreads();
        } else {
            zbuf[tid & 511] = 0.0f;
            __syncthreads();
        }
        // ---- phase 2: gates, state update, tagged publish ----
        if (tid < 128) {
            const float zi = zbuf[pb * 128 +      pd] + z0;
            const float zf = zbuf[pb * 128 + 32 + pd] + z1;
            const float zg = zbuf[pb * 128 + 64 + pd] + z2;
            const float zo = zbuf[pb * 128 + 96 + pd] + z3;
            c_state = sigf(zf) * c_state + sigf(zi) * tanhf_fast(zg);
            const float h = sigf(zo) * tanhf_fast(c_state);
            const int row = bt_layout ? (gb * 64 + t) : (t * 128 + gb);
            outbuf[(size_t)row * 512 + dir * 256 + dim] = h;
            const unsigned long long val =
                (((unsigned long long)(tag_base + tt + 1)) << 32) | __float_as_uint(h);
            __hip_atomic_store(
                &hxt[((((size_t)(tt & 1)) * 2 + dir) * 32 + q) * 1024 + (dim << 2) + pb],
                val, __ATOMIC_RELAXED, __HIP_MEMORY_SCOPE_AGENT);
        }
        __syncthreads();   // protect hbuf/zbuf before next iteration
    }
}

// ---------------- attention pooling (unchanged) ----------------------------
__global__ __launch_bounds__(256) void k_attnpool(
    const float* __restrict__ hbar, const float* __restrict__ outp,
    const float* __restrict__ ws2, float* __restrict__ sent)
{
    __shared__ float hb[64][132];
    __shared__ float w2[8][128];
    __shared__ float att[8][64];
    const int b = blockIdx.x, tid = threadIdx.x;
    for (int i = tid; i < 1024; i += 256) ((float*)w2)[i] = ws2[i];
    const float* hsrc = hbar + (size_t)b * 64 * 128;
    for (int i = tid; i < 2048; i += 256) {
        const int row = i >> 5, d4 = (i & 31) << 2;
        *(float4*)&hb[row][d4] = *(const float4*)(hsrc + row * 128 + d4);
    }
    __syncthreads();
    for (int p = tid; p < 512; p += 256) {
        const int r = p >> 6, t = p & 63;
        float s = 0.0f;
        #pragma unroll 8
        for (int d = 0; d < 128; d += 4) {
            const float4 x = *(const float4*)&hb[t][d];
            const float4 y = *(const float4*)&w2[r][d];
            s += x.x * y.x + x.y * y.y + x.z * y.z + x.w * y.w;
        }
        att[r][t] = s;
    }
    __syncthreads();
    const float* ob = outp + (size_t)b * 64 * 512;
    float s0[8] = {}, s1[8] = {};
    for (int t = 0; t < 64; ++t) {
        const float v0 = ob[t * 512 + tid];
        const float v1 = ob[t * 512 + 256 + tid];
        #pragma unroll
        for (int r = 0; r < 8; ++r) {
            const float a = att[r][t];
            s0[r] += a * v0; s1[r] += a * v1;
        }
    }
    #pragma unroll
    for (int r = 0; r < 8; ++r) {
        sent[((size_t)b * 8 + r) * 512 + tid]       = s0[r];
        sent[((size_t)b * 8 + r) * 512 + 256 + tid] = s1[r];
    }
}

// ---------------- dynamic routing (unchanged) ------------------------------
__global__ __launch_bounds__(512) void k_routing(
    const float* __restrict__ votes, float* __restrict__ out)
{
    __shared__ float v[8][32][16];
    __shared__ float logits[8][32];
    __shared__ float route[8][32];
    const int b = blockIdx.x, tid = threadIdx.x;
    const float* vb = votes + (size_t)b * 4096;
    for (int i = tid; i < 4096; i += 512) ((float*)v)[i] = vb[i];
    if (tid < 256) ((float*)logits)[tid] = 0.0f;
    __syncthreads();
    const int c = tid >> 4, a = tid & 15;
    float n2 = 0.0f;
    for (int it = 0; it < 3; ++it) {
        if (tid < 256) {
            const int r = tid >> 5, cc = tid & 31;
            const float l = logits[r][cc];
            float mx = l;
            #pragma unroll
            for (int m = 1; m < 32; m <<= 1) mx = fmaxf(mx, __shfl_xor(mx, m));
            const float e = __expf(l - mx);
            float sm = e;
            #pragma unroll
            for (int m = 1; m < 32; m <<= 1) sm += __shfl_xor(sm, m);
            route[r][cc] = e / sm;
        }
        __syncthreads();
        float pa = 0.0f;
        #pragma unroll
        for (int r = 0; r < 8; ++r) pa += route[r][c] * v[r][c][a];
        n2 = pa * pa;
        #pragma unroll
        for (int m = 1; m < 16; m <<= 1) n2 += __shfl_xor(n2, m);
        const float nrm = sqrtf(n2);
        const float av = pa * (nrm / (0.5f + n2));
        if (it < 2) {
            #pragma unroll
            for (int r = 0; r < 8; ++r) {
                float u = v[r][c][a] * av;
                #pragma unroll
                for (int m = 1; m < 16; m <<= 1) u += __shfl_xor(u, m);
                if (a == 0) logits[r][c] += u;
            }
        }
        __syncthreads();
    }
    if (a == 0) out[b * 32 + c] = n2 / (0.5f + n2);
}

// ---------------------------------------------------------------------------
static void launch_scan(const float* Z, const float* wf, const float* wb,
                        float* ob, int bt, unsigned long long* hxt, int tag_base,
                        hipStream_t stream)
{
    int base0 = 0;
    void* args[] = {(void*)&Z, (void*)&wf, (void*)&wb, (void*)&ob,
                    (void*)&bt, (void*)&hxt, (void*)&tag_base, (void*)&base0};
    if (hipLaunchCooperativeKernel((const void*)k_scan6, dim3(512), dim3(512),
                                   args, 0, stream) != hipSuccess) {
        k_scan6<<<dim3(256), 512, 0, stream>>>(Z, wf, wb, ob, bt, hxt, tag_base, 0);
        k_scan6<<<dim3(256), 512, 0, stream>>>(Z, wf, wb, ob, bt, hxt, tag_base, 256);
    }
}

extern "C" void kernel_launch(void* const* d_in, const int* in_sizes, int n_in,
                              void* d_out, int out_size, void* d_ws, size_t ws_size,
                              hipStream_t stream) {
    (void)in_sizes; (void)n_in; (void)out_size; (void)ws_size;
    const int*   tokens  = (const int*)d_in[0];
    const float* emb     = (const float*)d_in[2];
    const float* w_ih_f0 = (const float*)d_in[3];
    const float* w_hh_f0 = (const float*)d_in[4];
    const float* b_f0    = (const float*)d_in[5];
    const float* w_ih_b0 = (const float*)d_in[6];
    const float* w_hh_b0 = (const float*)d_in[7];
    const float* b_b0    = (const float*)d_in[8];
    const float* w_ih_f1 = (const float*)d_in[9];
    const float* w_hh_f1 = (const float*)d_in[10];
    const float* b_f1    = (const float*)d_in[11];
    const float* w_ih_b1 = (const float*)d_in[12];
    const float* w_hh_b1 = (const float*)d_in[13];
    const float* b_b1    = (const float*)d_in[14];
    const float* ws1     = (const float*)d_in[15];
    const float* ws2     = (const float*)d_in[16];
    const float* caps    = (const float*)d_in[17];

    float* wsf  = (float*)d_ws;
    float* Wt   = wsf;                          //  4 * 262144
    float* Z    = Wt   + 4 * 262144;            //  8192*2048
    float* x1   = Z    + 16777216;              //  8192*512
    float* outp = x1   + 4194304;               //  8192*512
    float* hbar = outp + 4194304;               //  8192*128
    float* sent = hbar + 1048576;               //  128*8*512
    float* vote = sent + 524288;                //  128*8*512
    unsigned long long* hxt = (unsigned long long*)(vote + 524288);  // 131072 u64 (1MB)
    float* out  = (float*)d_out;

    // bf16 split scratch aliases [outp, hbar) — dead before outp/hbar written.
    unsigned short* bs = (unsigned short*)outp;
    unsigned short* Ahi0 = bs;                       // layer-0 (Kp=320)
    unsigned short* Alo0 = Ahi0 + 8192 * 320;
    unsigned short* Whi0 = Alo0 + 8192 * 320;
    unsigned short* Wlo0 = Whi0 + 2048 * 320;
    unsigned short* Ahi1 = bs;                       // layer-1 (Kp=512)
    unsigned short* Alo1 = Ahi1 + 8192 * 512;
    unsigned short* Whi1 = Alo1 + 8192 * 512;
    unsigned short* Wlo1 = Whi1 + 2048 * 512;

    // 0. zero exchange tags (every launch; replay-safe)
    k_zero<<<dim3(1024), 256, 0, stream>>>((int*)hxt, 262144);
    // 1. transpose recurrent weights
    k_transpose<<<dim3(32, 8, 4), dim3(32, 8), 0, stream>>>(w_hh_f0, w_hh_b0, w_hh_f1, w_hh_b1, Wt);
    // 2. split layer-0 operands to (hi,lo) bf16
    k_split<<<dim3(2560), 256, 0, stream>>>(emb, tokens, 300, 320, Ahi0, Alo0);
    k_split<<<dim3(320),  256, 0, stream>>>(w_ih_f0, (const int*)nullptr, 300, 320, Whi0, Wlo0);
    k_split<<<dim3(320),  256, 0, stream>>>(w_ih_b0, (const int*)nullptr, 300, 320,
                                            Whi0 + 1024 * 320, Wlo0 + 1024 * 320);
    // 3. layer-0 projection (bf16x3 MFMA) -> Z
    k_mgemm<<<dim3(64, 16), 256, 0, stream>>>(Ahi0, Alo0, Whi0, Wlo0, b_f0, b_b0, 1024,
                                              Z, 2048, 320);
    // 4. layer-0 scan -> x1 [t*128+b][512]  (tags 1..64)
    launch_scan(Z, Wt, Wt + 262144, x1, 0, hxt, 0, stream);
    // 5. split layer-1 operands
    k_split<<<dim3(4096), 256, 0, stream>>>(x1, (const int*)nullptr, 512, 512, Ahi1, Alo1);
    k_split<<<dim3(512),  256, 0, stream>>>(w_ih_f1, (const int*)nullptr, 512, 512, Whi1, Wlo1);
    k_split<<<dim3(512),  256, 0, stream>>>(w_ih_b1, (const int*)nullptr, 512, 512,
                                            Whi1 + 1024 * 512, Wlo1 + 1024 * 512);
    // 6. layer-1 projection (bf16x3 MFMA) -> Z
    k_mgemm<<<dim3(64, 16), 256, 0, stream>>>(Ahi1, Alo1, Whi1, Wlo1, b_f1, b_b1, 1024,
                                              Z, 2048, 512);
    // 7. layer-1 scan -> outp [b*64+t][512]  (tags 65..128)
    launch_scan(Z, Wt + 2 * 262144, Wt + 3 * 262144, outp, 1, hxt, 64, stream);
    // 8. hbar = tanh(outp @ ws1^T)
    k_gemm<<<dim3(64, 1, 1), 256, 0, stream>>>(
        outp, 512, (const int*)nullptr, ws1, (const float*)nullptr, 1 << 30, 512,
        (const float*)nullptr, (const float*)nullptr,
        hbar, 128, 512, 1, 1, 0LL, 0LL, 0LL);
    // 9. attention + sent
    k_attnpool<<<dim3(128), 256, 0, stream>>>(hbar, outp, ws2, sent);
    // 10. votes
    k_gemm<<<dim3(1, 4, 8), 256, 0, stream>>>(
        sent, 4096, (const int*)nullptr, caps, (const float*)nullptr, 1 << 30, 512,
        (const float*)nullptr, (const float*)nullptr,
        vote, 4096, 512, 0, 0, 512LL, 262144LL, 512LL);
    // 11. routing
    k_routing<<<dim3(128), 512, 0, stream>>>(vote, out);
}

// Round 11
// 756.001 us; speedup vs baseline: 1.2022x; 1.2022x over previous
//
#include <hip/hip_runtime.h>
#include <hip/hip_bf16.h>

// ---------------------------------------------------------------------------
// CapsuleNetwork: embedding -> 2-layer BiLSTM -> attn pooling -> routing
// Round 10: revert scan to R8 flag protocol (best, 291us) but keep R9's
// conflict-free interleaved-k phase1 + linear hx layout. Fold the fp32->
// (hi,lo)bf16 split INTO k_mgemm staging (kills all 6 k_split kernels).
// B=128 T=64 E=300 H=256 DA=128 R=8 SC=32 AT=16
// ---------------------------------------------------------------------------

typedef __attribute__((ext_vector_type(8))) short bf16x8;
typedef __attribute__((ext_vector_type(4))) float f32x4;

__device__ __forceinline__ float sigf(float x) { return 1.0f / (1.0f + __expf(-x)); }
__device__ __forceinline__ float tanhf_fast(float x) { return 1.0f - 2.0f / (__expf(2.0f * x) + 1.0f); }

#define DPPF(v, ctrl) __int_as_float(__builtin_amdgcn_update_dpp(0, __float_as_int(v), ctrl, 0xF, 0xF, true))

// ---------------- transpose w_hh [1024][256] -> Wt [256][1024] -------------
__global__ void k_transpose(const float* __restrict__ w0, const float* __restrict__ w1,
                            const float* __restrict__ w2, const float* __restrict__ w3,
                            float* __restrict__ wt)
{
    __shared__ float tile[32][33];
    const float* W = (blockIdx.z == 0) ? w0 : (blockIdx.z == 1) ? w1 : (blockIdx.z == 2) ? w2 : w3;
    float* Wt = wt + (size_t)blockIdx.z * 256 * 1024;
    const int j0 = blockIdx.x * 32, k0 = blockIdx.y * 32;
    const int tx = threadIdx.x, ty = threadIdx.y;  // (32,8)
    #pragma unroll
    for (int i = 0; i < 32; i += 8)
        tile[ty + i][tx] = W[(size_t)(j0 + ty + i) * 256 + (k0 + tx)];
    __syncthreads();
    #pragma unroll
    for (int i = 0; i < 32; i += 8)
        Wt[(size_t)(k0 + ty + i) * 1024 + (j0 + tx)] = tile[tx][ty + i];
}

// ---------------- zero words -----------------------------------------------
__global__ void k_zero(int* __restrict__ p, int n)
{
    const int i = blockIdx.x * blockDim.x + threadIdx.x;
    if (i < n) p[i] = 0;
}

// ---------------- bf16x3 MFMA GEMM with INLINE fp32->hi/lo split -----------
// C[m][n] = sum_k A[m,k]*W[n,k] + bias[n]. A,W read as fp32 (A optionally
// token-gathered), split to (hi,lo) bf16 in-register during staging.
// 3 MFMAs per fragment (hh + hl + lh). Tile 128x128, 4 waves (2x2 of 64x64),
// 4x4 frags of 16x16x32, LDS stride 40 (2-way aliasing, free).
// Fragment layout (empirically verified R8/R9): A/B lane l: row/col=l&15,
// k-chunk (l>>4)*8; C/D: col=lane&15, row=(lane>>4)*4+reg.
__global__ __launch_bounds__(256) void k_mgemm(
    const float* __restrict__ A, int lda, const int* __restrict__ tokens,
    const float* __restrict__ W0, const float* __restrict__ W1, int ldw,
    const float* __restrict__ bias0, const float* __restrict__ bias1,
    float* __restrict__ C, int ldc, int Kin, int Kp)
{
    __shared__ unsigned short lAh[128 * 40];
    __shared__ unsigned short lAl[128 * 40];
    __shared__ unsigned short lBh[128 * 40];
    __shared__ unsigned short lBl[128 * 40];

    const int tid = threadIdx.x;
    const int m0 = blockIdx.x * 128;
    const int n0 = blockIdx.y * 128;
    const int w  = tid >> 6, l = tid & 63;
    const int wm = (w >> 1) * 64, wn = (w & 1) * 64;
    const int lr = l & 15, lk = (l >> 4) * 8;

    // staging coords (2 chunks of 8 k per thread)
    int srow[2], sk8[2];
    const float* arow[2];
    const float* wrow[2];
    #pragma unroll
    for (int p = 0; p < 2; ++p) {
        const int chunk = tid + p * 256;
        srow[p] = chunk >> 2;
        sk8[p]  = (chunk & 3) * 8;
        const int am = m0 + srow[p];
        if (tokens) {
            const int t = am >> 7, b = am & 127;
            arow[p] = A + (size_t)tokens[b * 64 + t] * lda;
        } else {
            arow[p] = A + (size_t)am * lda;
        }
        const int wnr = n0 + srow[p];
        wrow[p] = (wnr < 1024) ? (W0 + (size_t)wnr * ldw)
                               : (W1 + (size_t)(wnr - 1024) * ldw);
    }

    f32x4 acc[4][4];
    #pragma unroll
    for (int i = 0; i < 4; ++i)
        #pragma unroll
        for (int j = 0; j < 4; ++j)
            acc[i][j] = (f32x4){0.f, 0.f, 0.f, 0.f};

    float fa[2][8], fw[2][8];
    // prologue: prefetch tile 0 (fp32, guarded at Kin)
    #pragma unroll
    for (int p = 0; p < 2; ++p) {
        const int k0 = sk8[p];
        if (k0 + 7 < Kin) {
            const float4 a0 = *(const float4*)(arow[p] + k0);
            const float4 a1 = *(const float4*)(arow[p] + k0 + 4);
            fa[p][0]=a0.x; fa[p][1]=a0.y; fa[p][2]=a0.z; fa[p][3]=a0.w;
            fa[p][4]=a1.x; fa[p][5]=a1.y; fa[p][6]=a1.z; fa[p][7]=a1.w;
            const float4 b0 = *(const float4*)(wrow[p] + k0);
            const float4 b1 = *(const float4*)(wrow[p] + k0 + 4);
            fw[p][0]=b0.x; fw[p][1]=b0.y; fw[p][2]=b0.z; fw[p][3]=b0.w;
            fw[p][4]=b1.x; fw[p][5]=b1.y; fw[p][6]=b1.z; fw[p][7]=b1.w;
        } else {
            #pragma unroll
            for (int j = 0; j < 8; ++j) {
                fa[p][j] = (k0 + j < Kin) ? arow[p][k0 + j] : 0.0f;
                fw[p][j] = (k0 + j < Kin) ? wrow[p][k0 + j] : 0.0f;
            }
        }
    }

    for (int kt = 0; kt < Kp; kt += 32) {
        // ---- split + write prefetched regs to LDS ----
        #pragma unroll
        for (int p = 0; p < 2; ++p) {
            const int la = srow[p] * 40 + sk8[p];
            ushort hA[8], lA[8], hW[8], lW[8];
            #pragma unroll
            for (int j = 0; j < 8; ++j) {
                __hip_bfloat16 bh = __float2bfloat16(fa[p][j]);
                const float fh = __bfloat162float(bh);
                __hip_bfloat16 bl = __float2bfloat16(fa[p][j] - fh);
                hA[j] = *(ushort*)&bh; lA[j] = *(ushort*)&bl;
                __hip_bfloat16 wh = __float2bfloat16(fw[p][j]);
                const float fwh = __bfloat162float(wh);
                __hip_bfloat16 wl = __float2bfloat16(fw[p][j] - fwh);
                hW[j] = *(ushort*)&wh; lW[j] = *(ushort*)&wl;
            }
            *(bf16x8*)&lAh[la] = *(bf16x8*)hA;
            *(bf16x8*)&lAl[la] = *(bf16x8*)lA;
            *(bf16x8*)&lBh[la] = *(bf16x8*)hW;
            *(bf16x8*)&lBl[la] = *(bf16x8*)lW;
        }
        __syncthreads();
        // ---- prefetch next tile (hidden under MFMAs) ----
        if (kt + 32 < Kp) {
            #pragma unroll
            for (int p = 0; p < 2; ++p) {
                const int k0 = kt + 32 + sk8[p];
                if (k0 + 7 < Kin) {
                    const float4 a0 = *(const float4*)(arow[p] + k0);
                    const float4 a1 = *(const float4*)(arow[p] + k0 + 4);
                    fa[p][0]=a0.x; fa[p][1]=a0.y; fa[p][2]=a0.z; fa[p][3]=a0.w;
                    fa[p][4]=a1.x; fa[p][5]=a1.y; fa[p][6]=a1.z; fa[p][7]=a1.w;
                    const float4 b0 = *(const float4*)(wrow[p] + k0);
                    const float4 b1 = *(const float4*)(wrow[p] + k0 + 4);
                    fw[p][0]=b0.x; fw[p][1]=b0.y; fw[p][2]=b0.z; fw[p][3]=b0.w;
                    fw[p][4]=b1.x; fw[p][5]=b1.y; fw[p][6]=b1.z; fw[p][7]=b1.w;
                } else {
                    #pragma unroll
                    for (int j = 0; j < 8; ++j) {
                        fa[p][j] = (k0 + j < Kin) ? arow[p][k0 + j] : 0.0f;
                        fw[p][j] = (k0 + j < Kin) ? wrow[p][k0 + j] : 0.0f;
                    }
                }
            }
        }
        // ---- fragments + 48 MFMAs ----
        bf16x8 ah[4], al[4], bh[4], bl[4];
        #pragma unroll
        for (int f = 0; f < 4; ++f) {
            const int ra = (wm + f * 16 + lr) * 40 + lk;
            const int rb = (wn + f * 16 + lr) * 40 + lk;
            ah[f] = *(const bf16x8*)&lAh[ra];
            al[f] = *(const bf16x8*)&lAl[ra];
            bh[f] = *(const bf16x8*)&lBh[rb];
            bl[f] = *(const bf16x8*)&lBl[rb];
        }
        #pragma unroll
        for (int fm = 0; fm < 4; ++fm)
            #pragma unroll
            for (int fn = 0; fn < 4; ++fn) {
                acc[fm][fn] = __builtin_amdgcn_mfma_f32_16x16x32_bf16(ah[fm], bh[fn], acc[fm][fn], 0, 0, 0);
                acc[fm][fn] = __builtin_amdgcn_mfma_f32_16x16x32_bf16(ah[fm], bl[fn], acc[fm][fn], 0, 0, 0);
                acc[fm][fn] = __builtin_amdgcn_mfma_f32_16x16x32_bf16(al[fm], bh[fn], acc[fm][fn], 0, 0, 0);
            }
        __syncthreads();
    }
    // ---- epilogue ----
    #pragma unroll
    for (int fm = 0; fm < 4; ++fm)
        #pragma unroll
        for (int fn = 0; fn < 4; ++fn) {
            const int col = n0 + wn + fn * 16 + lr;
            const float bv = (col < 1024) ? (bias0 ? bias0[col] : 0.f)
                                          : (bias1 ? bias1[col - 1024] : 0.f);
            #pragma unroll
            for (int j = 0; j < 4; ++j) {
                const int row = m0 + wm + fm * 16 + (l >> 4) * 4 + j;
                C[(size_t)row * ldc + col] = acc[fm][fn][j] + bv;
            }
        }
}

// ---------------- fp32 GEMM (R6) — used for hbar & votes only --------------
__global__ __launch_bounds__(256) void k_gemm(
    const float* __restrict__ A, int lda, const int* __restrict__ tokens,
    const float* __restrict__ W0, const float* __restrict__ W1, int nsplit, int ldw,
    const float* __restrict__ bias0, const float* __restrict__ bias1,
    float* __restrict__ C, int ldc, int K, int transb, int act_tanh,
    long long sA, long long sW, long long sC)
{
    __shared__ float As[32][128];
    __shared__ float Ws[32][128];
    A  += (size_t)blockIdx.z * (size_t)sA;
    W0 += (size_t)blockIdx.z * (size_t)sW;
    C  += (size_t)blockIdx.z * (size_t)sC;
    const int tid = threadIdx.x;
    const int m0 = blockIdx.x * 128;
    const int n0 = blockIdx.y * 128;

    const int srow = tid >> 1;
    const int kh   = (tid & 1) * 16;
    const int am = m0 + srow;
    const float* arow;
    if (tokens) {
        const int t = am >> 7, b = am & 127;
        arow = A + (size_t)tokens[b * 64 + t] * lda;
    } else {
        arow = A + (size_t)am * lda;
    }
    const int wn = n0 + srow;
    const float* wrow = (wn < nsplit) ? (W0 + (size_t)wn * ldw)
                                      : (W1 + (size_t)(wn - nsplit) * ldw);
    const int kw = tid >> 3;
    const int n8 = (tid & 7) * 16;

    const int tm4 = (tid & 15) * 4;
    const int tn4 = (tid >> 4) * 4;
    float acc[8][8] = {};
    float4 ra[4], rw[4];

    const int nt = (K + 31) / 32;

    #pragma unroll
    for (int j = 0; j < 4; ++j) {
        const int k = kh + j * 4;
        if (k + 3 < K) ra[j] = *(const float4*)(arow + k);
        else {
            float t0 = (k + 0 < K) ? arow[k + 0] : 0.f;
            float t1 = (k + 1 < K) ? arow[k + 1] : 0.f;
            float t2 = (k + 2 < K) ? arow[k + 2] : 0.f;
            float t3 = (k + 3 < K) ? arow[k + 3] : 0.f;
            ra[j] = make_float4(t0, t1, t2, t3);
        }
    }
    if (transb) {
        #pragma unroll
        for (int j = 0; j < 4; ++j) {
            const int k = kh + j * 4;
            if (k + 3 < K) rw[j] = *(const float4*)(wrow + k);
            else {
                float t0 = (k + 0 < K) ? wrow[k + 0] : 0.f;
                float t1 = (k + 1 < K) ? wrow[k + 1] : 0.f;
                float t2 = (k + 2 < K) ? wrow[k + 2] : 0.f;
                float t3 = (k + 3 < K) ? wrow[k + 3] : 0.f;
                rw[j] = make_float4(t0, t1, t2, t3);
            }
        }
    } else {
        const float* src = (kw < K) ? (W0 + (size_t)kw * ldw + n0 + n8) : W0;
        #pragma unroll
        for (int j = 0; j < 4; ++j)
            rw[j] = (kw < K) ? *(const float4*)(src + j * 4) : make_float4(0, 0, 0, 0);
    }

    for (int tile = 0; tile < nt; ++tile) {
        #pragma unroll
        for (int j = 0; j < 4; ++j) {
            As[kh + j * 4 + 0][srow] = ra[j].x;
            As[kh + j * 4 + 1][srow] = ra[j].y;
            As[kh + j * 4 + 2][srow] = ra[j].z;
            As[kh + j * 4 + 3][srow] = ra[j].w;
        }
        if (transb) {
            #pragma unroll
            for (int j = 0; j < 4; ++j) {
                Ws[kh + j * 4 + 0][srow] = rw[j].x;
                Ws[kh + j * 4 + 1][srow] = rw[j].y;
                Ws[kh + j * 4 + 2][srow] = rw[j].z;
                Ws[kh + j * 4 + 3][srow] = rw[j].w;
            }
        } else {
            #pragma unroll
            for (int j = 0; j < 4; ++j)
                *(float4*)&Ws[kw][n8 + j * 4] = rw[j];
        }
        __syncthreads();
        if (tile + 1 < nt) {
            const int kb = (tile + 1) * 32;
            #pragma unroll
            for (int j = 0; j < 4; ++j) {
                const int k = kb + kh + j * 4;
                if (k + 3 < K) ra[j] = *(const float4*)(arow + k);
                else {
                    float t0 = (k + 0 < K) ? arow[k + 0] : 0.f;
                    float t1 = (k + 1 < K) ? arow[k + 1] : 0.f;
                    float t2 = (k + 2 < K) ? arow[k + 2] : 0.f;
                    float t3 = (k + 3 < K) ? arow[k + 3] : 0.f;
                    ra[j] = make_float4(t0, t1, t2, t3);
                }
            }
            if (transb) {
                #pragma unroll
                for (int j = 0; j < 4; ++j) {
                    const int k = kb + kh + j * 4;
                    if (k + 3 < K) rw[j] = *(const float4*)(wrow + k);
                    else {
                        float t0 = (k + 0 < K) ? wrow[k + 0] : 0.f;
                        float t1 = (k + 1 < K) ? wrow[k + 1] : 0.f;
                        float t2 = (k + 2 < K) ? wrow[k + 2] : 0.f;
                        float t3 = (k + 3 < K) ? wrow[k + 3] : 0.f;
                        rw[j] = make_float4(t0, t1, t2, t3);
                    }
                }
            } else {
                const int k = kb + kw;
                const float* src = (k < K) ? (W0 + (size_t)k * ldw + n0 + n8) : W0;
                #pragma unroll
                for (int j = 0; j < 4; ++j)
                    rw[j] = (k < K) ? *(const float4*)(src + j * 4) : make_float4(0, 0, 0, 0);
            }
        }
        #pragma unroll 8
        for (int kk = 0; kk < 32; ++kk) {
            const float4 a0 = *(const float4*)&As[kk][tm4];
            const float4 a1 = *(const float4*)&As[kk][tm4 + 64];
            const float4 b0 = *(const float4*)&Ws[kk][tn4];
            const float4 b1 = *(const float4*)&Ws[kk][tn4 + 64];
            const float av[8] = {a0.x, a0.y, a0.z, a0.w, a1.x, a1.y, a1.z, a1.w};
            const float bv[8] = {b0.x, b0.y, b0.z, b0.w, b1.x, b1.y, b1.z, b1.w};
            #pragma unroll
            for (int i = 0; i < 8; ++i)
                #pragma unroll
                for (int j = 0; j < 8; ++j)
                    acc[i][j] += av[i] * bv[j];
        }
        __syncthreads();
    }
    const int half = (n0 >= nsplit) ? 1 : 0;
    const float* bp = half ? bias1 : bias0;
    const int nl = n0 - (half ? nsplit : 0);
    #pragma unroll
    for (int i = 0; i < 8; ++i) {
        const int row = m0 + tm4 + (i >> 2) * 64 + (i & 3);
        #pragma unroll
        for (int jh = 0; jh < 2; ++jh) {
            float v[4];
            #pragma unroll
            for (int j = 0; j < 4; ++j) {
                float x = acc[i][jh * 4 + j];
                if (bp) x += bp[nl + tn4 + jh * 64 + j];
                if (act_tanh) x = tanhf_fast(x);
                v[j] = x;
            }
            *(float4*)(C + (size_t)row * ldc + n0 + tn4 + jh * 64) =
                make_float4(v[0], v[1], v[2], v[3]);
        }
    }
}

// ---------------- BiLSTM scan: R8 flag protocol + R9 conflict-free phase1 --
// 512 blocks x 512 thr (2/CU). bx = dir*256 + s*32 + q. W[32][2] in regs
// (rows k = i*8+ks to match interleaved phase1). hx layout [dim*4+b] so
// staging is a linear coalesced copy (0 LDS conflicts, R9-verified).
// Exchange: RELAXED agent atomics; ordering from __syncthreads vmcnt(0)
// drain before the flag add (R4-verified mechanism).
__global__ __launch_bounds__(512, 4) void k_scan7(
    const float* __restrict__ Zin, const float* __restrict__ WtF,
    const float* __restrict__ WtB, float* __restrict__ outbuf,
    int bt_layout, float* __restrict__ hx, int* __restrict__ flags, int bx_base)
{
    __shared__ __align__(16) float hbuf[1024];   // [dim][4b] linear
    __shared__ float zbuf[512];                  // [4b][128 local cols]

    const int bx  = blockIdx.x + bx_base;
    const int dir = bx >> 8;
    const int s   = (bx & 255) >> 5;
    const int q   = bx & 31;
    const int tid = threadIdx.x;
    const int cg  = tid >> 3;          // 0..63 col group (2 cols)
    const int ks  = tid & 7;           // 0..7  k lane
    const float* __restrict__ Wt = dir ? WtB : WtF;

    const int gate = cg >> 4;          // 0..3
    const int wg   = cg & 15;          // 0..15
    const int colbase = gate * 256 + s * 32 + wg * 2;
    // W rows k = i*8+ks (interleaved to match phase1)
    float W[32][2];
    {
        const float* wp = Wt + (size_t)ks * 1024 + colbase;
        #pragma unroll
        for (int i = 0; i < 32; ++i) {
            const float2 w2 = *(const float2*)(wp + (size_t)i * 8192);
            W[i][0] = w2.x; W[i][1] = w2.y;
        }
    }

    const int pb  = tid >> 5;          // batch 0..3   (phase2, tid<128)
    const int pd  = tid & 31;          // local dim
    const int dim = s * 32 + pd;
    const int gb  = q * 4 + pb;
    float c_state = 0.0f;
    const int fbase = (dir * 32 + q) * 64;

    for (int tt = 0; tt < 64; ++tt) {
        const int t = dir ? (63 - tt) : tt;
        float z0 = 0.f, z1 = 0.f, z2 = 0.f, z3 = 0.f;
        if (tid < 128) {
            const float* zr = Zin + (size_t)(t * 128 + gb) * 2048 + dir * 1024 + dim;
            z0 = zr[0]; z1 = zr[256]; z2 = zr[512]; z3 = zr[768];
        }
        if (tt > 0) {
            if (tid == 0) {
                while (__hip_atomic_load(&flags[fbase + tt - 1], __ATOMIC_RELAXED,
                                         __HIP_MEMORY_SCOPE_AGENT) < 8)
                    __builtin_amdgcn_s_sleep(1);
            }
            __syncthreads();
            // ---- linear staging ([dim][4b] layout) ----
            {
                const float* hsrc = hx + ((((size_t)((tt - 1) & 1)) * 2 + dir) * 32 + q) * 1024;
                hbuf[tid]       = __hip_atomic_load(&hsrc[tid], __ATOMIC_RELAXED,
                                                    __HIP_MEMORY_SCOPE_AGENT);
                hbuf[tid + 512] = __hip_atomic_load(&hsrc[tid + 512], __ATOMIC_RELAXED,
                                                    __HIP_MEMORY_SCOPE_AGENT);
            }
            __syncthreads();
            // ---- phase 1: interleaved-k partial dot (conflict-free) ----
            float acc[4][2] = {};
            #pragma unroll
            for (int i = 0; i < 32; ++i) {
                const int k = i * 8 + ks;
                const float4 h4 = *(const float4*)&hbuf[k << 2];
                acc[0][0] += h4.x * W[i][0]; acc[0][1] += h4.x * W[i][1];
                acc[1][0] += h4.y * W[i][0]; acc[1][1] += h4.y * W[i][1];
                acc[2][0] += h4.z * W[i][0]; acc[2][1] += h4.z * W[i][1];
                acc[3][0] += h4.w * W[i][0]; acc[3][1] += h4.w * W[i][1];
            }
            // ---- DPP butterfly all-reduce over the 8 ks-lanes ----
            #pragma unroll
            for (int b = 0; b < 4; ++b)
                #pragma unroll
                for (int c = 0; c < 2; ++c) {
                    float v = acc[b][c];
                    v += DPPF(v, 0xB1);                  // xor 1
                    v += DPPF(v, 0x4E);                  // xor 2
                    v += DPPF(DPPF(v, 0x141), 0x1B);     // xor 4
                    acc[b][c] = v;
                }
            #pragma unroll
            for (int a = 0; a < 8; ++a)
                if (ks == a)
                    zbuf[(a >> 1) * 128 + gate * 32 + wg * 2 + (a & 1)] = acc[a >> 1][a & 1];
            __syncthreads();
        } else {
            zbuf[tid & 511] = 0.0f;
            __syncthreads();
        }
        // ---- phase 2: gates, state update, publish h ----
        if (tid < 128) {
            const float zi = zbuf[pb * 128 +      pd] + z0;
            const float zf = zbuf[pb * 128 + 32 + pd] + z1;
            const float zg = zbuf[pb * 128 + 64 + pd] + z2;
            const float zo = zbuf[pb * 128 + 96 + pd] + z3;
            c_state = sigf(zf) * c_state + sigf(zi) * tanhf_fast(zg);
            const float h = sigf(zo) * tanhf_fast(c_state);
            const int row = bt_layout ? (gb * 64 + t) : (t * 128 + gb);
            outbuf[(size_t)row * 512 + dir * 256 + dim] = h;
            __hip_atomic_store(
                &hx[(((size_t)(tt & 1)) * 2 + dir) * 32768 + (size_t)q * 1024 + (dim << 2) + pb],
                h, __ATOMIC_RELAXED, __HIP_MEMORY_SCOPE_AGENT);
        }
        __syncthreads();  // vmcnt(0) drain: h stores complete before flag add
        if (tid == 0)
            __hip_atomic_fetch_add(&flags[fbase + tt], 1, __ATOMIC_RELAXED,
                                   __HIP_MEMORY_SCOPE_AGENT);
    }
}

// ---------------- attention pooling (unchanged) ----------------------------
__global__ __launch_bounds__(256) void k_attnpool(
    const float* __restrict__ hbar, const float* __restrict__ outp,
    const float* __restrict__ ws2, float* __restrict__ sent)
{
    __shared__ float hb[64][132];
    __shared__ float w2[8][128];
    __shared__ float att[8][64];
    const int b = blockIdx.x, tid = threadIdx.x;
    for (int i = tid; i < 1024; i += 256) ((float*)w2)[i] = ws2[i];
    const float* hsrc = hbar + (size_t)b * 64 * 128;
    for (int i = tid; i < 2048; i += 256) {
        const int row = i >> 5, d4 = (i & 31) << 2;
        *(float4*)&hb[row][d4] = *(const float4*)(hsrc + row * 128 + d4);
    }
    __syncthreads();
    for (int p = tid; p < 512; p += 256) {
        const int r = p >> 6, t = p & 63;
        float s = 0.0f;
        #pragma unroll 8
        for (int d = 0; d < 128; d += 4) {
            const float4 x = *(const float4*)&hb[t][d];
            const float4 y = *(const float4*)&w2[r][d];
            s += x.x * y.x + x.y * y.y + x.z * y.z + x.w * y.w;
        }
        att[r][t] = s;
    }
    __syncthreads();
    const float* ob = outp + (size_t)b * 64 * 512;
    float s0[8] = {}, s1[8] = {};
    for (int t = 0; t < 64; ++t) {
        const float v0 = ob[t * 512 + tid];
        const float v1 = ob[t * 512 + 256 + tid];
        #pragma unroll
        for (int r = 0; r < 8; ++r) {
            const float a = att[r][t];
            s0[r] += a * v0; s1[r] += a * v1;
        }
    }
    #pragma unroll
    for (int r = 0; r < 8; ++r) {
        sent[((size_t)b * 8 + r) * 512 + tid]       = s0[r];
        sent[((size_t)b * 8 + r) * 512 + 256 + tid] = s1[r];
    }
}

// ---------------- dynamic routing (unchanged) ------------------------------
__global__ __launch_bounds__(512) void k_routing(
    const float* __restrict__ votes, float* __restrict__ out)
{
    __shared__ float v[8][32][16];
    __shared__ float logits[8][32];
    __shared__ float route[8][32];
    const int b = blockIdx.x, tid = threadIdx.x;
    const float* vb = votes + (size_t)b * 4096;
    for (int i = tid; i < 4096; i += 512) ((float*)v)[i] = vb[i];
    if (tid < 256) ((float*)logits)[tid] = 0.0f;
    __syncthreads();
    const int c = tid >> 4, a = tid & 15;
    float n2 = 0.0f;
    for (int it = 0; it < 3; ++it) {
        if (tid < 256) {
            const int r = tid >> 5, cc = tid & 31;
            const float l = logits[r][cc];
            float mx = l;
            #pragma unroll
            for (int m = 1; m < 32; m <<= 1) mx = fmaxf(mx, __shfl_xor(mx, m));
            const float e = __expf(l - mx);
            float sm = e;
            #pragma unroll
            for (int m = 1; m < 32; m <<= 1) sm += __shfl_xor(sm, m);
            route[r][cc] = e / sm;
        }
        __syncthreads();
        float pa = 0.0f;
        #pragma unroll
        for (int r = 0; r < 8; ++r) pa += route[r][c] * v[r][c][a];
        n2 = pa * pa;
        #pragma unroll
        for (int m = 1; m < 16; m <<= 1) n2 += __shfl_xor(n2, m);
        const float nrm = sqrtf(n2);
        const float av = pa * (nrm / (0.5f + n2));
        if (it < 2) {
            #pragma unroll
            for (int r = 0; r < 8; ++r) {
                float u = v[r][c][a] * av;
                #pragma unroll
                for (int m = 1; m < 16; m <<= 1) u += __shfl_xor(u, m);
                if (a == 0) logits[r][c] += u;
            }
        }
        __syncthreads();
    }
    if (a == 0) out[b * 32 + c] = n2 / (0.5f + n2);
}

// ---------------------------------------------------------------------------
static void launch_scan(const float* Z, const float* wf, const float* wb,
                        float* ob, int bt, float* hx, int* fl, hipStream_t stream)
{
    int base0 = 0;
    void* args[] = {(void*)&Z, (void*)&wf, (void*)&wb, (void*)&ob,
                    (void*)&bt, (void*)&hx, (void*)&fl, (void*)&base0};
    if (hipLaunchCooperativeKernel((const void*)k_scan7, dim3(512), dim3(512),
                                   args, 0, stream) != hipSuccess) {
        k_scan7<<<dim3(256), 512, 0, stream>>>(Z, wf, wb, ob, bt, hx, fl, 0);
        k_scan7<<<dim3(256), 512, 0, stream>>>(Z, wf, wb, ob, bt, hx, fl, 256);
    }
}

extern "C" void kernel_launch(void* const* d_in, const int* in_sizes, int n_in,
                              void* d_out, int out_size, void* d_ws, size_t ws_size,
                              hipStream_t stream) {
    (void)in_sizes; (void)n_in; (void)out_size; (void)ws_size;
    const int*   tokens  = (const int*)d_in[0];
    const float* emb     = (const float*)d_in[2];
    const float* w_ih_f0 = (const float*)d_in[3];
    const float* w_hh_f0 = (const float*)d_in[4];
    const float* b_f0    = (const float*)d_in[5];
    const float* w_ih_b0 = (const float*)d_in[6];
    const float* w_hh_b0 = (const float*)d_in[7];
    const float* b_b0    = (const float*)d_in[8];
    const float* w_ih_f1 = (const float*)d_in[9];
    const float* w_hh_f1 = (const float*)d_in[10];
    const float* b_f1    = (const float*)d_in[11];
    const float* w_ih_b1 = (const float*)d_in[12];
    const float* w_hh_b1 = (const float*)d_in[13];
    const float* b_b1    = (const float*)d_in[14];
    const float* ws1     = (const float*)d_in[15];
    const float* ws2     = (const float*)d_in[16];
    const float* caps    = (const float*)d_in[17];

    float* wsf  = (float*)d_ws;
    float* Wt   = wsf;                          //  4 * 262144
    float* Z    = Wt   + 4 * 262144;            //  8192*2048
    float* x1   = Z    + 16777216;              //  8192*512
    float* outp = x1   + 4194304;               //  8192*512
    float* hbar = outp + 4194304;               //  8192*128
    float* sent = hbar + 1048576;               //  128*8*512
    float* vote = sent + 524288;                //  128*8*512
    float* hx   = vote + 524288;                //  2*2*32*1024 = 131072
    int*   flags = (int*)(hx + 131072);         //  2 * 4096 ints
    float* out  = (float*)d_out;

    // 0. zero sync flags (every launch; replays don't re-poison)
    k_zero<<<dim3(32), 256, 0, stream>>>(flags, 8192);
    // 1. transpose recurrent weights
    k_transpose<<<dim3(32, 8, 4), dim3(32, 8), 0, stream>>>(w_hh_f0, w_hh_b0, w_hh_f1, w_hh_b1, Wt);
    // 2. layer-0 projection (bf16x3 MFMA, inline gather+split) -> Z
    k_mgemm<<<dim3(64, 16), 256, 0, stream>>>(
        emb, 300, tokens, w_ih_f0, w_ih_b0, 300, b_f0, b_b0, Z, 2048, 300, 320);
    // 3. layer-0 scan -> x1 [t*128+b][512]
    launch_scan(Z, Wt, Wt + 262144, x1, 0, hx, flags, stream);
    // 4. layer-1 projection (bf16x3 MFMA, inline split) -> Z
    k_mgemm<<<dim3(64, 16), 256, 0, stream>>>(
        x1, 512, (const int*)nullptr, w_ih_f1, w_ih_b1, 512, b_f1, b_b1, Z, 2048, 512, 512);
    // 5. layer-1 scan -> outp [b*64+t][512]
    launch_scan(Z, Wt + 2 * 262144, Wt + 3 * 262144, outp, 1, hx, flags + 4096, stream);
    // 6. hbar = tanh(outp @ ws1^T)
    k_gemm<<<dim3(64, 1, 1), 256, 0, stream>>>(
        outp, 512, (const int*)nullptr, ws1, (const float*)nullptr, 1 << 30, 512,
        (const float*)nullptr, (const float*)nullptr,
        hbar, 128, 512, 1, 1, 0LL, 0LL, 0LL);
    // 7. attention + sent
    k_attnpool<<<dim3(128), 256, 0, stream>>>(hbar, outp, ws2, sent);
    // 8. votes
    k_gemm<<<dim3(1, 4, 8), 256, 0, stream>>>(
        sent, 4096, (const int*)nullptr, caps, (const float*)nullptr, 1 << 30, 512,
        (const float*)nullptr, (const float*)nullptr,
        vote, 4096, 512, 0, 0, 512LL, 262144LL, 512LL);
    // 9. routing
    k_routing<<<dim3(128), 512, 0, stream>>>(vote, out);
}

// Round 13
// 730.539 us; speedup vs baseline: 1.2441x; 1.0349x over previous
//
#include <hip/hip_runtime.h>
#include <hip/hip_bf16.h>

// ---------------------------------------------------------------------------
// CapsuleNetwork: embedding -> 2-layer BiLSTM -> attn pooling -> routing
// Round 12 (resubmit of R11 — infra failure, no data):
// scan k-split 16 x 4 cols/thread (halves phase-1 ds_read count, the
// measured dominant cost); u64 paired staging loads; hbar via k_mgemm+tanh.
// B=128 T=64 E=300 H=256 DA=128 R=8 SC=32 AT=16
// ---------------------------------------------------------------------------

typedef __attribute__((ext_vector_type(8))) short bf16x8;
typedef __attribute__((ext_vector_type(4))) float f32x4;

__device__ __forceinline__ float sigf(float x) { return 1.0f / (1.0f + __expf(-x)); }
__device__ __forceinline__ float tanhf_fast(float x) { return 1.0f - 2.0f / (__expf(2.0f * x) + 1.0f); }

#define DPPF(v, ctrl) __int_as_float(__builtin_amdgcn_update_dpp(0, __float_as_int(v), ctrl, 0xF, 0xF, true))

// ---------------- transpose w_hh [1024][256] -> Wt [256][1024] -------------
__global__ void k_transpose(const float* __restrict__ w0, const float* __restrict__ w1,
                            const float* __restrict__ w2, const float* __restrict__ w3,
                            float* __restrict__ wt)
{
    __shared__ float tile[32][33];
    const float* W = (blockIdx.z == 0) ? w0 : (blockIdx.z == 1) ? w1 : (blockIdx.z == 2) ? w2 : w3;
    float* Wt = wt + (size_t)blockIdx.z * 256 * 1024;
    const int j0 = blockIdx.x * 32, k0 = blockIdx.y * 32;
    const int tx = threadIdx.x, ty = threadIdx.y;  // (32,8)
    #pragma unroll
    for (int i = 0; i < 32; i += 8)
        tile[ty + i][tx] = W[(size_t)(j0 + ty + i) * 256 + (k0 + tx)];
    __syncthreads();
    #pragma unroll
    for (int i = 0; i < 32; i += 8)
        Wt[(size_t)(k0 + ty + i) * 1024 + (j0 + tx)] = tile[tx][ty + i];
}

// ---------------- zero words -----------------------------------------------
__global__ void k_zero(int* __restrict__ p, int n)
{
    const int i = blockIdx.x * blockDim.x + threadIdx.x;
    if (i < n) p[i] = 0;
}

// ---------------- bf16x3 MFMA GEMM with INLINE fp32->hi/lo split -----------
// C[m][n] = act( sum_k A[m,k]*W[n,k] + bias[n] ). A,W read as fp32 (A
// optionally token-gathered), split to (hi,lo) bf16 in-register at staging.
// 3 MFMAs per fragment (hh + hl + lh). Tile 128x128, 4 waves (2x2 of 64x64),
// 4x4 frags of 16x16x32, LDS stride 40.
__global__ __launch_bounds__(256) void k_mgemm(
    const float* __restrict__ A, int lda, const int* __restrict__ tokens,
    const float* __restrict__ W0, const float* __restrict__ W1, int ldw,
    const float* __restrict__ bias0, const float* __restrict__ bias1,
    float* __restrict__ C, int ldc, int Kin, int Kp, int act_tanh)
{
    __shared__ unsigned short lAh[128 * 40];
    __shared__ unsigned short lAl[128 * 40];
    __shared__ unsigned short lBh[128 * 40];
    __shared__ unsigned short lBl[128 * 40];

    const int tid = threadIdx.x;
    const int m0 = blockIdx.x * 128;
    const int n0 = blockIdx.y * 128;
    const int w  = tid >> 6, l = tid & 63;
    const int wm = (w >> 1) * 64, wn = (w & 1) * 64;
    const int lr = l & 15, lk = (l >> 4) * 8;

    int srow[2], sk8[2];
    const float* arow[2];
    const float* wrow[2];
    #pragma unroll
    for (int p = 0; p < 2; ++p) {
        const int chunk = tid + p * 256;
        srow[p] = chunk >> 2;
        sk8[p]  = (chunk & 3) * 8;
        const int am = m0 + srow[p];
        if (tokens) {
            const int t = am >> 7, b = am & 127;
            arow[p] = A + (size_t)tokens[b * 64 + t] * lda;
        } else {
            arow[p] = A + (size_t)am * lda;
        }
        const int wnr = n0 + srow[p];
        wrow[p] = (wnr < 1024) ? (W0 + (size_t)wnr * ldw)
                               : (W1 + (size_t)(wnr - 1024) * ldw);
    }

    f32x4 acc[4][4];
    #pragma unroll
    for (int i = 0; i < 4; ++i)
        #pragma unroll
        for (int j = 0; j < 4; ++j)
            acc[i][j] = (f32x4){0.f, 0.f, 0.f, 0.f};

    float fa[2][8], fw[2][8];
    #pragma unroll
    for (int p = 0; p < 2; ++p) {
        const int k0 = sk8[p];
        if (k0 + 7 < Kin) {
            const float4 a0 = *(const float4*)(arow[p] + k0);
            const float4 a1 = *(const float4*)(arow[p] + k0 + 4);
            fa[p][0]=a0.x; fa[p][1]=a0.y; fa[p][2]=a0.z; fa[p][3]=a0.w;
            fa[p][4]=a1.x; fa[p][5]=a1.y; fa[p][6]=a1.z; fa[p][7]=a1.w;
            const float4 b0 = *(const float4*)(wrow[p] + k0);
            const float4 b1 = *(const float4*)(wrow[p] + k0 + 4);
            fw[p][0]=b0.x; fw[p][1]=b0.y; fw[p][2]=b0.z; fw[p][3]=b0.w;
            fw[p][4]=b1.x; fw[p][5]=b1.y; fw[p][6]=b1.z; fw[p][7]=b1.w;
        } else {
            #pragma unroll
            for (int j = 0; j < 8; ++j) {
                fa[p][j] = (k0 + j < Kin) ? arow[p][k0 + j] : 0.0f;
                fw[p][j] = (k0 + j < Kin) ? wrow[p][k0 + j] : 0.0f;
            }
        }
    }

    for (int kt = 0; kt < Kp; kt += 32) {
        #pragma unroll
        for (int p = 0; p < 2; ++p) {
            const int la = srow[p] * 40 + sk8[p];
            ushort hA[8], lA[8], hW[8], lW[8];
            #pragma unroll
            for (int j = 0; j < 8; ++j) {
                __hip_bfloat16 bh = __float2bfloat16(fa[p][j]);
                const float fh = __bfloat162float(bh);
                __hip_bfloat16 bl = __float2bfloat16(fa[p][j] - fh);
                hA[j] = *(ushort*)&bh; lA[j] = *(ushort*)&bl;
                __hip_bfloat16 wh = __float2bfloat16(fw[p][j]);
                const float fwh = __bfloat162float(wh);
                __hip_bfloat16 wl = __float2bfloat16(fw[p][j] - fwh);
                hW[j] = *(ushort*)&wh; lW[j] = *(ushort*)&wl;
            }
            *(bf16x8*)&lAh[la] = *(bf16x8*)hA;
            *(bf16x8*)&lAl[la] = *(bf16x8*)lA;
            *(bf16x8*)&lBh[la] = *(bf16x8*)hW;
            *(bf16x8*)&lBl[la] = *(bf16x8*)lW;
        }
        __syncthreads();
        if (kt + 32 < Kp) {
            #pragma unroll
            for (int p = 0; p < 2; ++p) {
                const int k0 = kt + 32 + sk8[p];
                if (k0 + 7 < Kin) {
                    const float4 a0 = *(const float4*)(arow[p] + k0);
                    const float4 a1 = *(const float4*)(arow[p] + k0 + 4);
                    fa[p][0]=a0.x; fa[p][1]=a0.y; fa[p][2]=a0.z; fa[p][3]=a0.w;
                    fa[p][4]=a1.x; fa[p][5]=a1.y; fa[p][6]=a1.z; fa[p][7]=a1.w;
                    const float4 b0 = *(const float4*)(wrow[p] + k0);
                    const float4 b1 = *(const float4*)(wrow[p] + k0 + 4);
                    fw[p][0]=b0.x; fw[p][1]=b0.y; fw[p][2]=b0.z; fw[p][3]=b0.w;
                    fw[p][4]=b1.x; fw[p][5]=b1.y; fw[p][6]=b1.z; fw[p][7]=b1.w;
                } else {
                    #pragma unroll
                    for (int j = 0; j < 8; ++j) {
                        fa[p][j] = (k0 + j < Kin) ? arow[p][k0 + j] : 0.0f;
                        fw[p][j] = (k0 + j < Kin) ? wrow[p][k0 + j] : 0.0f;
                    }
                }
            }
        }
        bf16x8 ah[4], al[4], bh[4], bl[4];
        #pragma unroll
        for (int f = 0; f < 4; ++f) {
            const int ra = (wm + f * 16 + lr) * 40 + lk;
            const int rb = (wn + f * 16 + lr) * 40 + lk;
            ah[f] = *(const bf16x8*)&lAh[ra];
            al[f] = *(const bf16x8*)&lAl[ra];
            bh[f] = *(const bf16x8*)&lBh[rb];
            bl[f] = *(const bf16x8*)&lBl[rb];
        }
        #pragma unroll
        for (int fm = 0; fm < 4; ++fm)
            #pragma unroll
            for (int fn = 0; fn < 4; ++fn) {
                acc[fm][fn] = __builtin_amdgcn_mfma_f32_16x16x32_bf16(ah[fm], bh[fn], acc[fm][fn], 0, 0, 0);
                acc[fm][fn] = __builtin_amdgcn_mfma_f32_16x16x32_bf16(ah[fm], bl[fn], acc[fm][fn], 0, 0, 0);
                acc[fm][fn] = __builtin_amdgcn_mfma_f32_16x16x32_bf16(al[fm], bh[fn], acc[fm][fn], 0, 0, 0);
            }
        __syncthreads();
    }
    #pragma unroll
    for (int fm = 0; fm < 4; ++fm)
        #pragma unroll
        for (int fn = 0; fn < 4; ++fn) {
            const int col = n0 + wn + fn * 16 + lr;
            const float bv = (col < 1024) ? (bias0 ? bias0[col] : 0.f)
                                          : (bias1 ? bias1[col - 1024] : 0.f);
            #pragma unroll
            for (int j = 0; j < 4; ++j) {
                const int row = m0 + wm + fm * 16 + (l >> 4) * 4 + j;
                float x = acc[fm][fn][j] + bv;
                if (act_tanh) x = tanhf_fast(x);
                C[(size_t)row * ldc + col] = x;
            }
        }
}

// ---------------- fp32 GEMM (R6) — votes only ------------------------------
__global__ __launch_bounds__(256) void k_gemm(
    const float* __restrict__ A, int lda, const int* __restrict__ tokens,
    const float* __restrict__ W0, const float* __restrict__ W1, int nsplit, int ldw,
    const float* __restrict__ bias0, const float* __restrict__ bias1,
    float* __restrict__ C, int ldc, int K, int transb, int act_tanh,
    long long sA, long long sW, long long sC)
{
    __shared__ float As[32][128];
    __shared__ float Ws[32][128];
    A  += (size_t)blockIdx.z * (size_t)sA;
    W0 += (size_t)blockIdx.z * (size_t)sW;
    C  += (size_t)blockIdx.z * (size_t)sC;
    const int tid = threadIdx.x;
    const int m0 = blockIdx.x * 128;
    const int n0 = blockIdx.y * 128;

    const int srow = tid >> 1;
    const int kh   = (tid & 1) * 16;
    const int am = m0 + srow;
    const float* arow;
    if (tokens) {
        const int t = am >> 7, b = am & 127;
        arow = A + (size_t)tokens[b * 64 + t] * lda;
    } else {
        arow = A + (size_t)am * lda;
    }
    const int wn = n0 + srow;
    const float* wrow = (wn < nsplit) ? (W0 + (size_t)wn * ldw)
                                      : (W1 + (size_t)(wn - nsplit) * ldw);
    const int kw = tid >> 3;
    const int n8 = (tid & 7) * 16;

    const int tm4 = (tid & 15) * 4;
    const int tn4 = (tid >> 4) * 4;
    float acc[8][8] = {};
    float4 ra[4], rw[4];

    const int nt = (K + 31) / 32;

    #pragma unroll
    for (int j = 0; j < 4; ++j) {
        const int k = kh + j * 4;
        if (k + 3 < K) ra[j] = *(const float4*)(arow + k);
        else {
            float t0 = (k + 0 < K) ? arow[k + 0] : 0.f;
            float t1 = (k + 1 < K) ? arow[k + 1] : 0.f;
            float t2 = (k + 2 < K) ? arow[k + 2] : 0.f;
            float t3 = (k + 3 < K) ? arow[k + 3] : 0.f;
            ra[j] = make_float4(t0, t1, t2, t3);
        }
    }
    if (transb) {
        #pragma unroll
        for (int j = 0; j < 4; ++j) {
            const int k = kh + j * 4;
            if (k + 3 < K) rw[j] = *(const float4*)(wrow + k);
            else {
                float t0 = (k + 0 < K) ? wrow[k + 0] : 0.f;
                float t1 = (k + 1 < K) ? wrow[k + 1] : 0.f;
                float t2 = (k + 2 < K) ? wrow[k + 2] : 0.f;
                float t3 = (k + 3 < K) ? wrow[k + 3] : 0.f;
                rw[j] = make_float4(t0, t1, t2, t3);
            }
        }
    } else {
        const float* src = (kw < K) ? (W0 + (size_t)kw * ldw + n0 + n8) : W0;
        #pragma unroll
        for (int j = 0; j < 4; ++j)
            rw[j] = (kw < K) ? *(const float4*)(src + j * 4) : make_float4(0, 0, 0, 0);
    }

    for (int tile = 0; tile < nt; ++tile) {
        #pragma unroll
        for (int j = 0; j < 4; ++j) {
            As[kh + j * 4 + 0][srow] = ra[j].x;
            As[kh + j * 4 + 1][srow] = ra[j].y;
            As[kh + j * 4 + 2][srow] = ra[j].z;
            As[kh + j * 4 + 3][srow] = ra[j].w;
        }
        if (transb) {
            #pragma unroll
            for (int j = 0; j < 4; ++j) {
                Ws[kh + j * 4 + 0][srow] = rw[j].x;
                Ws[kh + j * 4 + 1][srow] = rw[j].y;
                Ws[kh + j * 4 + 2][srow] = rw[j].z;
                Ws[kh + j * 4 + 3][srow] = rw[j].w;
            }
        } else {
            #pragma unroll
            for (int j = 0; j < 4; ++j)
                *(float4*)&Ws[kw][n8 + j * 4] = rw[j];
        }
        __syncthreads();
        if (tile + 1 < nt) {
            const int kb = (tile + 1) * 32;
            #pragma unroll
            for (int j = 0; j < 4; ++j) {
                const int k = kb + kh + j * 4;
                if (k + 3 < K) ra[j] = *(const float4*)(arow + k);
                else {
                    float t0 = (k + 0 < K) ? arow[k + 0] : 0.f;
                    float t1 = (k + 1 < K) ? arow[k + 1] : 0.f;
                    float t2 = (k + 2 < K) ? arow[k + 2] : 0.f;
                    float t3 = (k + 3 < K) ? arow[k + 3] : 0.f;
                    ra[j] = make_float4(t0, t1, t2, t3);
                }
            }
            if (transb) {
                #pragma unroll
                for (int j = 0; j < 4; ++j) {
                    const int k = kb + kh + j * 4;
                    if (k + 3 < K) rw[j] = *(const float4*)(wrow + k);
                    else {
                        float t0 = (k + 0 < K) ? wrow[k + 0] : 0.f;
                        float t1 = (k + 1 < K) ? wrow[k + 1] : 0.f;
                        float t2 = (k + 2 < K) ? wrow[k + 2] : 0.f;
                        float t3 = (k + 3 < K) ? wrow[k + 3] : 0.f;
                        rw[j] = make_float4(t0, t1, t2, t3);
                    }
                }
            } else {
                const int k = kb + kw;
                const float* src = (k < K) ? (W0 + (size_t)k * ldw + n0 + n8) : W0;
                #pragma unroll
                for (int j = 0; j < 4; ++j)
                    rw[j] = (k < K) ? *(const float4*)(src + j * 4) : make_float4(0, 0, 0, 0);
            }
        }
        #pragma unroll 8
        for (int kk = 0; kk < 32; ++kk) {
            const float4 a0 = *(const float4*)&As[kk][tm4];
            const float4 a1 = *(const float4*)&As[kk][tm4 + 64];
            const float4 b0 = *(const float4*)&Ws[kk][tn4];
            const float4 b1 = *(const float4*)&Ws[kk][tn4 + 64];
            const float av[8] = {a0.x, a0.y, a0.z, a0.w, a1.x, a1.y, a1.z, a1.w};
            const float bv[8] = {b0.x, b0.y, b0.z, b0.w, b1.x, b1.y, b1.z, b1.w};
            #pragma unroll
            for (int i = 0; i < 8; ++i)
                #pragma unroll
                for (int j = 0; j < 8; ++j)
                    acc[i][j] += av[i] * bv[j];
        }
        __syncthreads();
    }
    const int half = (n0 >= nsplit) ? 1 : 0;
    const float* bp = half ? bias1 : bias0;
    const int nl = n0 - (half ? nsplit : 0);
    #pragma unroll
    for (int i = 0; i < 8; ++i) {
        const int row = m0 + tm4 + (i >> 2) * 64 + (i & 3);
        #pragma unroll
        for (int jh = 0; jh < 2; ++jh) {
            float v[4];
            #pragma unroll
            for (int j = 0; j < 4; ++j) {
                float x = acc[i][jh * 4 + j];
                if (bp) x += bp[nl + tn4 + jh * 64 + j];
                if (act_tanh) x = tanhf_fast(x);
                v[j] = x;
            }
            *(float4*)(C + (size_t)row * ldc + n0 + tn4 + jh * 64) =
                make_float4(v[0], v[1], v[2], v[3]);
        }
    }
}

// ---------------- BiLSTM scan: k-split 16 x 4 cols/thread ------------------
// 512 blocks x 512 thr (2/CU). bx = dir*256 + s*32 + q (same geometry/flags
// as R10 k_scan7). Thread: cg = tid>>4 (32 groups x 4 cols), ks = tid&15
// (16 k each, interleaved k = i*16+ks). Phase-1 h-reads HALVED: 16 b128 vs
// 32 (the measured LDS-pipe cost driver). W[16][4] float4 rows. 4-stage DPP
// butterfly over 16 ks-lanes (k_scan3-proven). u64 paired staging loads.
__global__ __launch_bounds__(512, 4) void k_scan8(
    const float* __restrict__ Zin, const float* __restrict__ WtF,
    const float* __restrict__ WtB, float* __restrict__ outbuf,
    int bt_layout, float* __restrict__ hx, int* __restrict__ flags, int bx_base)
{
    __shared__ __align__(16) float hbuf[1024];   // [dim][4b] linear
    __shared__ float zbuf[512];                  // [4b][128 local cols]

    const int bx  = blockIdx.x + bx_base;
    const int dir = bx >> 8;
    const int s   = (bx & 255) >> 5;
    const int q   = bx & 31;
    const int tid = threadIdx.x;
    const int cg  = tid >> 4;          // 0..31 col group (4 cols)
    const int ks  = tid & 15;          // 0..15 k lane (16 k each)
    const float* __restrict__ Wt = dir ? WtB : WtF;

    const int gate = cg >> 3;          // 0..3
    const int wg   = cg & 7;           // 0..7
    const int colbase = gate * 256 + s * 32 + wg * 4;
    // W rows k = i*16+ks, 4 cols each (float4 loads)
    float W[16][4];
    {
        const float* wp = Wt + (size_t)ks * 1024 + colbase;
        #pragma unroll
        for (int i = 0; i < 16; ++i) {
            const float4 w4 = *(const float4*)(wp + (size_t)i * 16384);
            W[i][0] = w4.x; W[i][1] = w4.y; W[i][2] = w4.z; W[i][3] = w4.w;
        }
    }

    const int pb  = tid >> 5;          // batch 0..3   (phase2, tid<128)
    const int pd  = tid & 31;          // local dim
    const int dim = s * 32 + pd;
    const int gb  = q * 4 + pb;
    float c_state = 0.0f;
    const int fbase = (dir * 32 + q) * 64;

    for (int tt = 0; tt < 64; ++tt) {
        const int t = dir ? (63 - tt) : tt;
        float z0 = 0.f, z1 = 0.f, z2 = 0.f, z3 = 0.f;
        if (tid < 128) {
            const float* zr = Zin + (size_t)(t * 128 + gb) * 2048 + dir * 1024 + dim;
            z0 = zr[0]; z1 = zr[256]; z2 = zr[512]; z3 = zr[768];
        }
        if (tt > 0) {
            if (tid == 0) {
                while (__hip_atomic_load(&flags[fbase + tt - 1], __ATOMIC_RELAXED,
                                         __HIP_MEMORY_SCOPE_AGENT) < 8)
                    __builtin_amdgcn_s_sleep(1);
            }
            __syncthreads();
            // ---- staging: one u64 atomic load (2 floats) per thread ----
            {
                const unsigned long long* hs64 = (const unsigned long long*)
                    (hx + ((((size_t)((tt - 1) & 1)) * 2 + dir) * 32 + q) * 1024);
                const unsigned long long v = __hip_atomic_load(&hs64[tid], __ATOMIC_RELAXED,
                                                               __HIP_MEMORY_SCOPE_AGENT);
                *(unsigned long long*)&hbuf[2 * tid] = v;
            }
            __syncthreads();
            // ---- phase 1: 16 iters, 1 b128 h-read + 16 FMA each ----
            float acc[4][4] = {};
            #pragma unroll
            for (int i = 0; i < 16; ++i) {
                const int k = i * 16 + ks;
                const float4 h4 = *(const float4*)&hbuf[k << 2];
                #pragma unroll
                for (int c = 0; c < 4; ++c) {
                    acc[0][c] += h4.x * W[i][c];
                    acc[1][c] += h4.y * W[i][c];
                    acc[2][c] += h4.z * W[i][c];
                    acc[3][c] += h4.w * W[i][c];
                }
            }
            // ---- 4-stage DPP butterfly over the 16 ks-lanes ----
            #pragma unroll
            for (int b = 0; b < 4; ++b)
                #pragma unroll
                for (int c = 0; c < 4; ++c) {
                    float v = acc[b][c];
                    v += DPPF(v, 0xB1);                  // xor 1
                    v += DPPF(v, 0x4E);                  // xor 2
                    v += DPPF(DPPF(v, 0x141), 0x1B);     // xor 4
                    v += DPPF(v, 0x128);                 // xor 8
                    acc[b][c] = v;
                }
            // lane ks writes value (b,c) = (ks>>2, ks&3)
            #pragma unroll
            for (int a = 0; a < 16; ++a)
                if (ks == a)
                    zbuf[(a >> 2) * 128 + gate * 32 + wg * 4 + (a & 3)] = acc[a >> 2][a & 3];
            __syncthreads();
        } else {
            zbuf[tid & 511] = 0.0f;
            __syncthreads();
        }
        // ---- phase 2: gates, state update, publish h ----
        if (tid < 128) {
            const float zi = zbuf[pb * 128 +      pd] + z0;
            const float zf = zbuf[pb * 128 + 32 + pd] + z1;
            const float zg = zbuf[pb * 128 + 64 + pd] + z2;
            const float zo = zbuf[pb * 128 + 96 + pd] + z3;
            c_state = sigf(zf) * c_state + sigf(zi) * tanhf_fast(zg);
            const float h = sigf(zo) * tanhf_fast(c_state);
            const int row = bt_layout ? (gb * 64 + t) : (t * 128 + gb);
            outbuf[(size_t)row * 512 + dir * 256 + dim] = h;
            __hip_atomic_store(
                &hx[(((size_t)(tt & 1)) * 2 + dir) * 32768 + (size_t)q * 1024 + (dim << 2) + pb],
                h, __ATOMIC_RELAXED, __HIP_MEMORY_SCOPE_AGENT);
        }
        __syncthreads();  // vmcnt(0) drain: h stores complete before flag add
        if (tid == 0)
            __hip_atomic_fetch_add(&flags[fbase + tt], 1, __ATOMIC_RELAXED,
                                   __HIP_MEMORY_SCOPE_AGENT);
    }
}

// ---------------- attention pooling (unchanged) ----------------------------
__global__ __launch_bounds__(256) void k_attnpool(
    const float* __restrict__ hbar, const float* __restrict__ outp,
    const float* __restrict__ ws2, float* __restrict__ sent)
{
    __shared__ float hb[64][132];
    __shared__ float w2[8][128];
    __shared__ float att[8][64];
    const int b = blockIdx.x, tid = threadIdx.x;
    for (int i = tid; i < 1024; i += 256) ((float*)w2)[i] = ws2[i];
    const float* hsrc = hbar + (size_t)b * 64 * 128;
    for (int i = tid; i < 2048; i += 256) {
        const int row = i >> 5, d4 = (i & 31) << 2;
        *(float4*)&hb[row][d4] = *(const float4*)(hsrc + row * 128 + d4);
    }
    __syncthreads();
    for (int p = tid; p < 512; p += 256) {
        const int r = p >> 6, t = p & 63;
        float s = 0.0f;
        #pragma unroll 8
        for (int d = 0; d < 128; d += 4) {
            const float4 x = *(const float4*)&hb[t][d];
            const float4 y = *(const float4*)&w2[r][d];
            s += x.x * y.x + x.y * y.y + x.z * y.z + x.w * y.w;
        }
        att[r][t] = s;
    }
    __syncthreads();
    const float* ob = outp + (size_t)b * 64 * 512;
    float s0[8] = {}, s1[8] = {};
    for (int t = 0; t < 64; ++t) {
        const float v0 = ob[t * 512 + tid];
        const float v1 = ob[t * 512 + 256 + tid];
        #pragma unroll
        for (int r = 0; r < 8; ++r) {
            const float a = att[r][t];
            s0[r] += a * v0; s1[r] += a * v1;
        }
    }
    #pragma unroll
    for (int r = 0; r < 8; ++r) {
        sent[((size_t)b * 8 + r) * 512 + tid]       = s0[r];
        sent[((size_t)b * 8 + r) * 512 + 256 + tid] = s1[r];
    }
}

// ---------------- dynamic routing (unchanged) ------------------------------
__global__ __launch_bounds__(512) void k_routing(
    const float* __restrict__ votes, float* __restrict__ out)
{
    __shared__ float v[8][32][16];
    __shared__ float logits[8][32];
    __shared__ float route[8][32];
    const int b = blockIdx.x, tid = threadIdx.x;
    const float* vb = votes + (size_t)b * 4096;
    for (int i = tid; i < 4096; i += 512) ((float*)v)[i] = vb[i];
    if (tid < 256) ((float*)logits)[tid] = 0.0f;
    __syncthreads();
    const int c = tid >> 4, a = tid & 15;
    float n2 = 0.0f;
    for (int it = 0; it < 3; ++it) {
        if (tid < 256) {
            const int r = tid >> 5, cc = tid & 31;
            const float l = logits[r][cc];
            float mx = l;
            #pragma unroll
            for (int m = 1; m < 32; m <<= 1) mx = fmaxf(mx, __shfl_xor(mx, m));
            const float e = __expf(l - mx);
            float sm = e;
            #pragma unroll
            for (int m = 1; m < 32; m <<= 1) sm += __shfl_xor(sm, m);
            route[r][cc] = e / sm;
        }
        __syncthreads();
        float pa = 0.0f;
        #pragma unroll
        for (int r = 0; r < 8; ++r) pa += route[r][c] * v[r][c][a];
        n2 = pa * pa;
        #pragma unroll
        for (int m = 1; m < 16; m <<= 1) n2 += __shfl_xor(n2, m);
        const float nrm = sqrtf(n2);
        const float av = pa * (nrm / (0.5f + n2));
        if (it < 2) {
            #pragma unroll
            for (int r = 0; r < 8; ++r) {
                float u = v[r][c][a] * av;
                #pragma unroll
                for (int m = 1; m < 16; m <<= 1) u += __shfl_xor(u, m);
                if (a == 0) logits[r][c] += u;
            }
        }
        __syncthreads();
    }
    if (a == 0) out[b * 32 + c] = n2 / (0.5f + n2);
}

// ---------------------------------------------------------------------------
static void launch_scan(const float* Z, const float* wf, const float* wb,
                        float* ob, int bt, float* hx, int* fl, hipStream_t stream)
{
    int base0 = 0;
    void* args[] = {(void*)&Z, (void*)&wf, (void*)&wb, (void*)&ob,
                    (void*)&bt, (void*)&hx, (void*)&fl, (void*)&base0};
    if (hipLaunchCooperativeKernel((const void*)k_scan8, dim3(512), dim3(512),
                                   args, 0, stream) != hipSuccess) {
        k_scan8<<<dim3(256), 512, 0, stream>>>(Z, wf, wb, ob, bt, hx, fl, 0);
        k_scan8<<<dim3(256), 512, 0, stream>>>(Z, wf, wb, ob, bt, hx, fl, 256);
    }
}

extern "C" void kernel_launch(void* const* d_in, const int* in_sizes, int n_in,
                              void* d_out, int out_size, void* d_ws, size_t ws_size,
                              hipStream_t stream) {
    (void)in_sizes; (void)n_in; (void)out_size; (void)ws_size;
    const int*   tokens  = (const int*)d_in[0];
    const float* emb     = (const float*)d_in[2];
    const float* w_ih_f0 = (const float*)d_in[3];
    const float* w_hh_f0 = (const float*)d_in[4];
    const float* b_f0    = (const float*)d_in[5];
    const float* w_ih_b0 = (const float*)d_in[6];
    const float* w_hh_b0 = (const float*)d_in[7];
    const float* b_b0    = (const float*)d_in[8];
    const float* w_ih_f1 = (const float*)d_in[9];
    const float* w_hh_f1 = (const float*)d_in[10];
    const float* b_f1    = (const float*)d_in[11];
    const float* w_ih_b1 = (const float*)d_in[12];
    const float* w_hh_b1 = (const float*)d_in[13];
    const float* b_b1    = (const float*)d_in[14];
    const float* ws1     = (const float*)d_in[15];
    const float* ws2     = (const float*)d_in[16];
    const float* caps    = (const float*)d_in[17];

    float* wsf  = (float*)d_ws;
    float* Wt   = wsf;                          //  4 * 262144
    float* Z    = Wt   + 4 * 262144;            //  8192*2048
    float* x1   = Z    + 16777216;              //  8192*512
    float* outp = x1   + 4194304;               //  8192*512
    float* hbar = outp + 4194304;               //  8192*128
    float* sent = hbar + 1048576;               //  128*8*512
    float* vote = sent + 524288;                //  128*8*512
    float* hx   = vote + 524288;                //  2*2*32*1024 = 131072
    int*   flags = (int*)(hx + 131072);         //  2 * 4096 ints
    float* out  = (float*)d_out;

    // 0. zero sync flags (every launch; replays don't re-poison)
    k_zero<<<dim3(32), 256, 0, stream>>>(flags, 8192);
    // 1. transpose recurrent weights
    k_transpose<<<dim3(32, 8, 4), dim3(32, 8), 0, stream>>>(w_hh_f0, w_hh_b0, w_hh_f1, w_hh_b1, Wt);
    // 2. layer-0 projection (bf16x3 MFMA, inline gather+split) -> Z
    k_mgemm<<<dim3(64, 16), 256, 0, stream>>>(
        emb, 300, tokens, w_ih_f0, w_ih_b0, 300, b_f0, b_b0, Z, 2048, 300, 320, 0);
    // 3. layer-0 scan -> x1 [t*128+b][512]
    launch_scan(Z, Wt, Wt + 262144, x1, 0, hx, flags, stream);
    // 4. layer-1 projection (bf16x3 MFMA, inline split) -> Z
    k_mgemm<<<dim3(64, 16), 256, 0, stream>>>(
        x1, 512, (const int*)nullptr, w_ih_f1, w_ih_b1, 512, b_f1, b_b1, Z, 2048, 512, 512, 0);
    // 5. layer-1 scan -> outp [b*64+t][512]
    launch_scan(Z, Wt + 2 * 262144, Wt + 3 * 262144, outp, 1, hx, flags + 4096, stream);
    // 6. hbar = tanh(outp @ ws1^T)  (MFMA + fused tanh)
    k_mgemm<<<dim3(64, 1), 256, 0, stream>>>(
        outp, 512, (const int*)nullptr, ws1, ws1, 512,
        (const float*)nullptr, (const float*)nullptr, hbar, 128, 512, 512, 1);
    // 7. attention + sent
    k_attnpool<<<dim3(128), 256, 0, stream>>>(hbar, outp, ws2, sent);
    // 8. votes
    k_gemm<<<dim3(1, 4, 8), 256, 0, stream>>>(
        sent, 4096, (const int*)nullptr, caps, (const float*)nullptr, 1 << 30, 512,
        (const float*)nullptr, (const float*)nullptr,
        vote, 4096, 512, 0, 0, 512LL, 262144LL, 512LL);
    // 9. routing
    k_routing<<<dim3(128), 512, 0, stream>>>(vote, out);
}

// Round 14
// 578.982 us; speedup vs baseline: 1.5697x; 1.2618x over previous
//
#include <hip/hip_runtime.h>
#include <hip/hip_bf16.h>

// ---------------------------------------------------------------------------
// CapsuleNetwork: embedding -> 2-layer BiLSTM -> attn pooling -> routing
// Round 13: MFMA-based scan. Per step, z[16b][128c] = h[16][256] @ W via
// bf16x3 16x16x32 MFMA (W resident in VGPR as bf16 hi/lo fragments; h
// exchanged as packed u32 bf16 pairs, staged to LDS). Replaces the VALU
// dot-product (75% VALUBusy in R12) with matrix cores. R8 flag protocol.
// B=128 T=64 E=300 H=256 DA=128 R=8 SC=32 AT=16
// ---------------------------------------------------------------------------

typedef __attribute__((ext_vector_type(8))) short bf16x8;
typedef __attribute__((ext_vector_type(4))) float f32x4;

__device__ __forceinline__ float sigf(float x) { return 1.0f / (1.0f + __expf(-x)); }
__device__ __forceinline__ float tanhf_fast(float x) { return 1.0f - 2.0f / (__expf(2.0f * x) + 1.0f); }

// ---------------- transpose w_hh [1024][256] -> Wt [256][1024] -------------
__global__ void k_transpose(const float* __restrict__ w0, const float* __restrict__ w1,
                            const float* __restrict__ w2, const float* __restrict__ w3,
                            float* __restrict__ wt)
{
    __shared__ float tile[32][33];
    const float* W = (blockIdx.z == 0) ? w0 : (blockIdx.z == 1) ? w1 : (blockIdx.z == 2) ? w2 : w3;
    float* Wt = wt + (size_t)blockIdx.z * 256 * 1024;
    const int j0 = blockIdx.x * 32, k0 = blockIdx.y * 32;
    const int tx = threadIdx.x, ty = threadIdx.y;  // (32,8)
    #pragma unroll
    for (int i = 0; i < 32; i += 8)
        tile[ty + i][tx] = W[(size_t)(j0 + ty + i) * 256 + (k0 + tx)];
    __syncthreads();
    #pragma unroll
    for (int i = 0; i < 32; i += 8)
        Wt[(size_t)(k0 + ty + i) * 1024 + (j0 + tx)] = tile[tx][ty + i];
}

// ---------------- zero words -----------------------------------------------
__global__ void k_zero(int* __restrict__ p, int n)
{
    const int i = blockIdx.x * blockDim.x + threadIdx.x;
    if (i < n) p[i] = 0;
}

// ---------------- bf16x3 MFMA GEMM with INLINE fp32->hi/lo split -----------
__global__ __launch_bounds__(256) void k_mgemm(
    const float* __restrict__ A, int lda, const int* __restrict__ tokens,
    const float* __restrict__ W0, const float* __restrict__ W1, int ldw,
    const float* __restrict__ bias0, const float* __restrict__ bias1,
    float* __restrict__ C, int ldc, int Kin, int Kp, int act_tanh)
{
    __shared__ unsigned short lAh[128 * 40];
    __shared__ unsigned short lAl[128 * 40];
    __shared__ unsigned short lBh[128 * 40];
    __shared__ unsigned short lBl[128 * 40];

    const int tid = threadIdx.x;
    const int m0 = blockIdx.x * 128;
    const int n0 = blockIdx.y * 128;
    const int w  = tid >> 6, l = tid & 63;
    const int wm = (w >> 1) * 64, wn = (w & 1) * 64;
    const int lr = l & 15, lk = (l >> 4) * 8;

    int srow[2], sk8[2];
    const float* arow[2];
    const float* wrow[2];
    #pragma unroll
    for (int p = 0; p < 2; ++p) {
        const int chunk = tid + p * 256;
        srow[p] = chunk >> 2;
        sk8[p]  = (chunk & 3) * 8;
        const int am = m0 + srow[p];
        if (tokens) {
            const int t = am >> 7, b = am & 127;
            arow[p] = A + (size_t)tokens[b * 64 + t] * lda;
        } else {
            arow[p] = A + (size_t)am * lda;
        }
        const int wnr = n0 + srow[p];
        wrow[p] = (wnr < 1024) ? (W0 + (size_t)wnr * ldw)
                               : (W1 + (size_t)(wnr - 1024) * ldw);
    }

    f32x4 acc[4][4];
    #pragma unroll
    for (int i = 0; i < 4; ++i)
        #pragma unroll
        for (int j = 0; j < 4; ++j)
            acc[i][j] = (f32x4){0.f, 0.f, 0.f, 0.f};

    float fa[2][8], fw[2][8];
    #pragma unroll
    for (int p = 0; p < 2; ++p) {
        const int k0 = sk8[p];
        if (k0 + 7 < Kin) {
            const float4 a0 = *(const float4*)(arow[p] + k0);
            const float4 a1 = *(const float4*)(arow[p] + k0 + 4);
            fa[p][0]=a0.x; fa[p][1]=a0.y; fa[p][2]=a0.z; fa[p][3]=a0.w;
            fa[p][4]=a1.x; fa[p][5]=a1.y; fa[p][6]=a1.z; fa[p][7]=a1.w;
            const float4 b0 = *(const float4*)(wrow[p] + k0);
            const float4 b1 = *(const float4*)(wrow[p] + k0 + 4);
            fw[p][0]=b0.x; fw[p][1]=b0.y; fw[p][2]=b0.z; fw[p][3]=b0.w;
            fw[p][4]=b1.x; fw[p][5]=b1.y; fw[p][6]=b1.z; fw[p][7]=b1.w;
        } else {
            #pragma unroll
            for (int j = 0; j < 8; ++j) {
                fa[p][j] = (k0 + j < Kin) ? arow[p][k0 + j] : 0.0f;
                fw[p][j] = (k0 + j < Kin) ? wrow[p][k0 + j] : 0.0f;
            }
        }
    }

    for (int kt = 0; kt < Kp; kt += 32) {
        #pragma unroll
        for (int p = 0; p < 2; ++p) {
            const int la = srow[p] * 40 + sk8[p];
            ushort hA[8], lA[8], hW[8], lW[8];
            #pragma unroll
            for (int j = 0; j < 8; ++j) {
                __hip_bfloat16 bh = __float2bfloat16(fa[p][j]);
                const float fh = __bfloat162float(bh);
                __hip_bfloat16 bl = __float2bfloat16(fa[p][j] - fh);
                hA[j] = *(ushort*)&bh; lA[j] = *(ushort*)&bl;
                __hip_bfloat16 wh = __float2bfloat16(fw[p][j]);
                const float fwh = __bfloat162float(wh);
                __hip_bfloat16 wl = __float2bfloat16(fw[p][j] - fwh);
                hW[j] = *(ushort*)&wh; lW[j] = *(ushort*)&wl;
            }
            *(bf16x8*)&lAh[la] = *(bf16x8*)hA;
            *(bf16x8*)&lAl[la] = *(bf16x8*)lA;
            *(bf16x8*)&lBh[la] = *(bf16x8*)hW;
            *(bf16x8*)&lBl[la] = *(bf16x8*)lW;
        }
        __syncthreads();
        if (kt + 32 < Kp) {
            #pragma unroll
            for (int p = 0; p < 2; ++p) {
                const int k0 = kt + 32 + sk8[p];
                if (k0 + 7 < Kin) {
                    const float4 a0 = *(const float4*)(arow[p] + k0);
                    const float4 a1 = *(const float4*)(arow[p] + k0 + 4);
                    fa[p][0]=a0.x; fa[p][1]=a0.y; fa[p][2]=a0.z; fa[p][3]=a0.w;
                    fa[p][4]=a1.x; fa[p][5]=a1.y; fa[p][6]=a1.z; fa[p][7]=a1.w;
                    const float4 b0 = *(const float4*)(wrow[p] + k0);
                    const float4 b1 = *(const float4*)(wrow[p] + k0 + 4);
                    fw[p][0]=b0.x; fw[p][1]=b0.y; fw[p][2]=b0.z; fw[p][3]=b0.w;
                    fw[p][4]=b1.x; fw[p][5]=b1.y; fw[p][6]=b1.z; fw[p][7]=b1.w;
                } else {
                    #pragma unroll
                    for (int j = 0; j < 8; ++j) {
                        fa[p][j] = (k0 + j < Kin) ? arow[p][k0 + j] : 0.0f;
                        fw[p][j] = (k0 + j < Kin) ? wrow[p][k0 + j] : 0.0f;
                    }
                }
            }
        }
        bf16x8 ah[4], al[4], bh[4], bl[4];
        #pragma unroll
        for (int f = 0; f < 4; ++f) {
            const int ra = (wm + f * 16 + lr) * 40 + lk;
            const int rb = (wn + f * 16 + lr) * 40 + lk;
            ah[f] = *(const bf16x8*)&lAh[ra];
            al[f] = *(const bf16x8*)&lAl[ra];
            bh[f] = *(const bf16x8*)&lBh[rb];
            bl[f] = *(const bf16x8*)&lBl[rb];
        }
        #pragma unroll
        for (int fm = 0; fm < 4; ++fm)
            #pragma unroll
            for (int fn = 0; fn < 4; ++fn) {
                acc[fm][fn] = __builtin_amdgcn_mfma_f32_16x16x32_bf16(ah[fm], bh[fn], acc[fm][fn], 0, 0, 0);
                acc[fm][fn] = __builtin_amdgcn_mfma_f32_16x16x32_bf16(ah[fm], bl[fn], acc[fm][fn], 0, 0, 0);
                acc[fm][fn] = __builtin_amdgcn_mfma_f32_16x16x32_bf16(al[fm], bh[fn], acc[fm][fn], 0, 0, 0);
            }
        __syncthreads();
    }
    #pragma unroll
    for (int fm = 0; fm < 4; ++fm)
        #pragma unroll
        for (int fn = 0; fn < 4; ++fn) {
            const int col = n0 + wn + fn * 16 + lr;
            const float bv = (col < 1024) ? (bias0 ? bias0[col] : 0.f)
                                          : (bias1 ? bias1[col - 1024] : 0.f);
            #pragma unroll
            for (int j = 0; j < 4; ++j) {
                const int row = m0 + wm + fm * 16 + (l >> 4) * 4 + j;
                float x = acc[fm][fn][j] + bv;
                if (act_tanh) x = tanhf_fast(x);
                C[(size_t)row * ldc + col] = x;
            }
        }
}

// ---------------- fp32 GEMM (R6) — votes only ------------------------------
__global__ __launch_bounds__(256) void k_gemm(
    const float* __restrict__ A, int lda, const int* __restrict__ tokens,
    const float* __restrict__ W0, const float* __restrict__ W1, int nsplit, int ldw,
    const float* __restrict__ bias0, const float* __restrict__ bias1,
    float* __restrict__ C, int ldc, int K, int transb, int act_tanh,
    long long sA, long long sW, long long sC)
{
    __shared__ float As[32][128];
    __shared__ float Ws[32][128];
    A  += (size_t)blockIdx.z * (size_t)sA;
    W0 += (size_t)blockIdx.z * (size_t)sW;
    C  += (size_t)blockIdx.z * (size_t)sC;
    const int tid = threadIdx.x;
    const int m0 = blockIdx.x * 128;
    const int n0 = blockIdx.y * 128;

    const int srow = tid >> 1;
    const int kh   = (tid & 1) * 16;
    const int am = m0 + srow;
    const float* arow;
    if (tokens) {
        const int t = am >> 7, b = am & 127;
        arow = A + (size_t)tokens[b * 64 + t] * lda;
    } else {
        arow = A + (size_t)am * lda;
    }
    const int wn = n0 + srow;
    const float* wrow = (wn < nsplit) ? (W0 + (size_t)wn * ldw)
                                      : (W1 + (size_t)(wn - nsplit) * ldw);
    const int kw = tid >> 3;
    const int n8 = (tid & 7) * 16;

    const int tm4 = (tid & 15) * 4;
    const int tn4 = (tid >> 4) * 4;
    float acc[8][8] = {};
    float4 ra[4], rw[4];

    const int nt = (K + 31) / 32;

    #pragma unroll
    for (int j = 0; j < 4; ++j) {
        const int k = kh + j * 4;
        if (k + 3 < K) ra[j] = *(const float4*)(arow + k);
        else {
            float t0 = (k + 0 < K) ? arow[k + 0] : 0.f;
            float t1 = (k + 1 < K) ? arow[k + 1] : 0.f;
            float t2 = (k + 2 < K) ? arow[k + 2] : 0.f;
            float t3 = (k + 3 < K) ? arow[k + 3] : 0.f;
            ra[j] = make_float4(t0, t1, t2, t3);
        }
    }
    if (transb) {
        #pragma unroll
        for (int j = 0; j < 4; ++j) {
            const int k = kh + j * 4;
            if (k + 3 < K) rw[j] = *(const float4*)(wrow + k);
            else {
                float t0 = (k + 0 < K) ? wrow[k + 0] : 0.f;
                float t1 = (k + 1 < K) ? wrow[k + 1] : 0.f;
                float t2 = (k + 2 < K) ? wrow[k + 2] : 0.f;
                float t3 = (k + 3 < K) ? wrow[k + 3] : 0.f;
                rw[j] = make_float4(t0, t1, t2, t3);
            }
        }
    } else {
        const float* src = (kw < K) ? (W0 + (size_t)kw * ldw + n0 + n8) : W0;
        #pragma unroll
        for (int j = 0; j < 4; ++j)
            rw[j] = (kw < K) ? *(const float4*)(src + j * 4) : make_float4(0, 0, 0, 0);
    }

    for (int tile = 0; tile < nt; ++tile) {
        #pragma unroll
        for (int j = 0; j < 4; ++j) {
            As[kh + j * 4 + 0][srow] = ra[j].x;
            As[kh + j * 4 + 1][srow] = ra[j].y;
            As[kh + j * 4 + 2][srow] = ra[j].z;
            As[kh + j * 4 + 3][srow] = ra[j].w;
        }
        if (transb) {
            #pragma unroll
            for (int j = 0; j < 4; ++j) {
                Ws[kh + j * 4 + 0][srow] = rw[j].x;
                Ws[kh + j * 4 + 1][srow] = rw[j].y;
                Ws[kh + j * 4 + 2][srow] = rw[j].z;
                Ws[kh + j * 4 + 3][srow] = rw[j].w;
            }
        } else {
            #pragma unroll
            for (int j = 0; j < 4; ++j)
                *(float4*)&Ws[kw][n8 + j * 4] = rw[j];
        }
        __syncthreads();
        if (tile + 1 < nt) {
            const int kb = (tile + 1) * 32;
            #pragma unroll
            for (int j = 0; j < 4; ++j) {
                const int k = kb + kh + j * 4;
                if (k + 3 < K) ra[j] = *(const float4*)(arow + k);
                else {
                    float t0 = (k + 0 < K) ? arow[k + 0] : 0.f;
                    float t1 = (k + 1 < K) ? arow[k + 1] : 0.f;
                    float t2 = (k + 2 < K) ? arow[k + 2] : 0.f;
                    float t3 = (k + 3 < K) ? arow[k + 3] : 0.f;
                    ra[j] = make_float4(t0, t1, t2, t3);
                }
            }
            if (transb) {
                #pragma unroll
                for (int j = 0; j < 4; ++j) {
                    const int k = kb + kh + j * 4;
                    if (k + 3 < K) rw[j] = *(const float4*)(wrow + k);
                    else {
                        float t0 = (k + 0 < K) ? wrow[k + 0] : 0.f;
                        float t1 = (k + 1 < K) ? wrow[k + 1] : 0.f;
                        float t2 = (k + 2 < K) ? wrow[k + 2] : 0.f;
                        float t3 = (k + 3 < K) ? wrow[k + 3] : 0.f;
                        rw[j] = make_float4(t0, t1, t2, t3);
                    }
                }
            } else {
                const int k = kb + kw;
                const float* src = (k < K) ? (W0 + (size_t)k * ldw + n0 + n8) : W0;
                #pragma unroll
                for (int j = 0; j < 4; ++j)
                    rw[j] = (k < K) ? *(const float4*)(src + j * 4) : make_float4(0, 0, 0, 0);
            }
        }
        #pragma unroll 8
        for (int kk = 0; kk < 32; ++kk) {
            const float4 a0 = *(const float4*)&As[kk][tm4];
            const float4 a1 = *(const float4*)&As[kk][tm4 + 64];
            const float4 b0 = *(const float4*)&Ws[kk][tn4];
            const float4 b1 = *(const float4*)&Ws[kk][tn4 + 64];
            const float av[8] = {a0.x, a0.y, a0.z, a0.w, a1.x, a1.y, a1.z, a1.w};
            const float bv[8] = {b0.x, b0.y, b0.z, b0.w, b1.x, b1.y, b1.z, b1.w};
            #pragma unroll
            for (int i = 0; i < 8; ++i)
                #pragma unroll
                for (int j = 0; j < 8; ++j)
                    acc[i][j] += av[i] * bv[j];
        }
        __syncthreads();
    }
    const int half = (n0 >= nsplit) ? 1 : 0;
    const float* bp = half ? bias1 : bias0;
    const int nl = n0 - (half ? nsplit : 0);
    #pragma unroll
    for (int i = 0; i < 8; ++i) {
        const int row = m0 + tm4 + (i >> 2) * 64 + (i & 3);
        #pragma unroll
        for (int jh = 0; jh < 2; ++jh) {
            float v[4];
            #pragma unroll
            for (int j = 0; j < 4; ++j) {
                float x = acc[i][jh * 4 + j];
                if (bp) x += bp[nl + tn4 + jh * 64 + j];
                if (act_tanh) x = tanhf_fast(x);
                v[j] = x;
            }
            *(float4*)(C + (size_t)row * ldc + n0 + tn4 + jh * 64) =
                make_float4(v[0], v[1], v[2], v[3]);
        }
    }
}

// ---------------- BiLSTM scan: MFMA recurrence -----------------------------
// 128 blocks x 512 thr (8 waves). bx = s*16 + g: g = dir*8+qg (group of 16
// batch rows), s = 0..7 (32 h-dims). Per step: z[16b][128c] = h[16][256] @
// W-slice via bf16x3 MFMA. Wave w = col-fragment (gate w>>1, dim-half w&1);
// W resident as bf16 hi/lo frags (64 VGPR). h exchanged as u32 (hi16|lo16)
// bf16 pairs; staged to LDS [16][264] u16 (2-way banks). R8 flag protocol.
__global__ __launch_bounds__(512, 2) void k_scan9(
    const float* __restrict__ Zin, const float* __restrict__ WtF,
    const float* __restrict__ WtB, float* __restrict__ outbuf,
    int bt_layout, unsigned int* __restrict__ hx32, int* __restrict__ flags,
    int bx_base)
{
    __shared__ __align__(16) unsigned short hbh[16 * 264];
    __shared__ __align__(16) unsigned short hbl[16 * 264];
    __shared__ float zbuf[8 * 16 * 17];          // [frag][bi][17]

    const int bx  = blockIdx.x + bx_base;
    const int g   = bx & 15;           // dir*8 + qg
    const int s   = bx >> 4;           // 0..7 dim slice
    const int dir = g >> 3;
    const int qg  = g & 7;
    const int tid = threadIdx.x;
    const int w   = tid >> 6;          // wave = fragment 0..7
    const int l   = tid & 63;
    const int lr  = l & 15;
    const int lk8 = (l >> 4) * 8;
    const float* __restrict__ Wt = dir ? WtB : WtF;

    // ---- W preload: fragment w -> gate = w>>1, dim-half = w&1 ----
    const int colg = (w >> 1) * 256 + s * 32 + (w & 1) * 16 + lr;
    bf16x8 wbh[8], wbl[8];
    #pragma unroll
    for (int kf = 0; kf < 8; ++kf) {
        ushort ph[8], pl[8];
        #pragma unroll
        for (int j = 0; j < 8; ++j) {
            const int k = kf * 32 + lk8 + j;
            const float v = Wt[(size_t)k * 1024 + colg];
            __hip_bfloat16 bh = __float2bfloat16(v);
            __hip_bfloat16 bl = __float2bfloat16(v - __bfloat162float(bh));
            ph[j] = *(ushort*)&bh; pl[j] = *(ushort*)&bl;
        }
        wbh[kf] = *(bf16x8*)ph;
        wbl[kf] = *(bf16x8*)pl;
    }

    // phase-2 / publish mapping: bi = tid>>5 (16 batch), di = tid&31 (32 dims)
    const int bi  = tid >> 5;
    const int di  = tid & 31;
    const int gb  = qg * 16 + bi;
    const int dim = s * 32 + di;
    float c_state = 0.0f;
    const int fbase = g * 64;
    // staging map: row = tid>>5, k8 = (tid&31)*8
    const int st_base = (tid >> 5) * 256 + (tid & 31) * 8;
    const int st_lds  = (tid >> 5) * 264 + (tid & 31) * 8;

    for (int tt = 0; tt < 64; ++tt) {
        const int t = dir ? (63 - tt) : tt;
        // Z prefetch (independent of h; overlaps poll)
        const float* zr = Zin + (size_t)(t * 128 + gb) * 2048 + dir * 1024 + dim;
        const float z0 = zr[0], z1 = zr[256], z2 = zr[512], z3 = zr[768];
        if (tt > 0) {
            if (tid == 0) {
                while (__hip_atomic_load(&flags[fbase + tt - 1], __ATOMIC_RELAXED,
                                         __HIP_MEMORY_SCOPE_AGENT) < 8)
                    __builtin_amdgcn_s_sleep(1);
            }
            __syncthreads();
            // ---- stage h: 8 u32 (4 u64 loads), unpack to bf16 hi/lo LDS ----
            {
                const unsigned long long* hs64 = (const unsigned long long*)
                    (hx32 + ((size_t)(((tt - 1) & 1) * 16 + g)) * 4096 + st_base);
                unsigned int hp[4], lp[4];
                #pragma unroll
                for (int j = 0; j < 4; ++j) {
                    const unsigned long long q = __hip_atomic_load(&hs64[j], __ATOMIC_RELAXED,
                                                                   __HIP_MEMORY_SCOPE_AGENT);
                    const unsigned int w0 = (unsigned int)q;
                    const unsigned int w1 = (unsigned int)(q >> 32);
                    hp[j] = (w0 >> 16) | (w1 & 0xFFFF0000u);
                    lp[j] = (w0 & 0xFFFFu) | (w1 << 16);
                }
                *(uint4*)&hbh[st_lds] = make_uint4(hp[0], hp[1], hp[2], hp[3]);
                *(uint4*)&hbl[st_lds] = make_uint4(lp[0], lp[1], lp[2], lp[3]);
            }
            __syncthreads();
            // ---- MFMA: 8 k-frags x 3 products ----
            f32x4 acc = (f32x4){0.f, 0.f, 0.f, 0.f};
            #pragma unroll
            for (int kf = 0; kf < 8; ++kf) {
                const int ao = lr * 264 + kf * 32 + lk8;
                const bf16x8 ah = *(const bf16x8*)&hbh[ao];
                const bf16x8 al = *(const bf16x8*)&hbl[ao];
                acc = __builtin_amdgcn_mfma_f32_16x16x32_bf16(ah, wbh[kf], acc, 0, 0, 0);
                acc = __builtin_amdgcn_mfma_f32_16x16x32_bf16(ah, wbl[kf], acc, 0, 0, 0);
                acc = __builtin_amdgcn_mfma_f32_16x16x32_bf16(al, wbh[kf], acc, 0, 0, 0);
            }
            // C layout: col = lr, row_b = (l>>4)*4 + j
            #pragma unroll
            for (int j = 0; j < 4; ++j)
                zbuf[(w * 16 + (l >> 4) * 4 + j) * 17 + lr] = acc[j];
            __syncthreads();
        } else {
            for (int i = tid; i < 2176; i += 512) zbuf[i] = 0.0f;
            __syncthreads();
        }
        // ---- phase 2: gates, state, publish (all 512 threads) ----
        {
            const int dh = di >> 4, dl = di & 15;
            const float zi = zbuf[((0 * 2 + dh) * 16 + bi) * 17 + dl] + z0;
            const float zf = zbuf[((1 * 2 + dh) * 16 + bi) * 17 + dl] + z1;
            const float zg = zbuf[((2 * 2 + dh) * 16 + bi) * 17 + dl] + z2;
            const float zo = zbuf[((3 * 2 + dh) * 16 + bi) * 17 + dl] + z3;
            c_state = sigf(zf) * c_state + sigf(zi) * tanhf_fast(zg);
            const float h = sigf(zo) * tanhf_fast(c_state);
            const int row = bt_layout ? (gb * 64 + t) : (t * 128 + gb);
            outbuf[(size_t)row * 512 + dir * 256 + dim] = h;
            __hip_bfloat16 bh = __float2bfloat16(h);
            __hip_bfloat16 bl = __float2bfloat16(h - __bfloat162float(bh));
            const unsigned int pk = ((unsigned int)(*(ushort*)&bh) << 16) | (*(ushort*)&bl);
            __hip_atomic_store(
                &hx32[((size_t)((tt & 1) * 16 + g)) * 4096 + bi * 256 + dim],
                pk, __ATOMIC_RELAXED, __HIP_MEMORY_SCOPE_AGENT);
        }
        __syncthreads();  // vmcnt(0) drain: publishes complete before flag add
        if (tid == 0)
            __hip_atomic_fetch_add(&flags[fbase + tt], 1, __ATOMIC_RELAXED,
                                   __HIP_MEMORY_SCOPE_AGENT);
    }
}

// ---------------- attention pooling (unchanged) ----------------------------
__global__ __launch_bounds__(256) void k_attnpool(
    const float* __restrict__ hbar, const float* __restrict__ outp,
    const float* __restrict__ ws2, float* __restrict__ sent)
{
    __shared__ float hb[64][132];
    __shared__ float w2[8][128];
    __shared__ float att[8][64];
    const int b = blockIdx.x, tid = threadIdx.x;
    for (int i = tid; i < 1024; i += 256) ((float*)w2)[i] = ws2[i];
    const float* hsrc = hbar + (size_t)b * 64 * 128;
    for (int i = tid; i < 2048; i += 256) {
        const int row = i >> 5, d4 = (i & 31) << 2;
        *(float4*)&hb[row][d4] = *(const float4*)(hsrc + row * 128 + d4);
    }
    __syncthreads();
    for (int p = tid; p < 512; p += 256) {
        const int r = p >> 6, t = p & 63;
        float s = 0.0f;
        #pragma unroll 8
        for (int d = 0; d < 128; d += 4) {
            const float4 x = *(const float4*)&hb[t][d];
            const float4 y = *(const float4*)&w2[r][d];
            s += x.x * y.x + x.y * y.y + x.z * y.z + x.w * y.w;
        }
        att[r][t] = s;
    }
    __syncthreads();
    const float* ob = outp + (size_t)b * 64 * 512;
    float s0[8] = {}, s1[8] = {};
    for (int t = 0; t < 64; ++t) {
        const float v0 = ob[t * 512 + tid];
        const float v1 = ob[t * 512 + 256 + tid];
        #pragma unroll
        for (int r = 0; r < 8; ++r) {
            const float a = att[r][t];
            s0[r] += a * v0; s1[r] += a * v1;
        }
    }
    #pragma unroll
    for (int r = 0; r < 8; ++r) {
        sent[((size_t)b * 8 + r) * 512 + tid]       = s0[r];
        sent[((size_t)b * 8 + r) * 512 + 256 + tid] = s1[r];
    }
}

// ---------------- dynamic routing (unchanged) ------------------------------
__global__ __launch_bounds__(512) void k_routing(
    const float* __restrict__ votes, float* __restrict__ out)
{
    __shared__ float v[8][32][16];
    __shared__ float logits[8][32];
    __shared__ float route[8][32];
    const int b = blockIdx.x, tid = threadIdx.x;
    const float* vb = votes + (size_t)b * 4096;
    for (int i = tid; i < 4096; i += 512) ((float*)v)[i] = vb[i];
    if (tid < 256) ((float*)logits)[tid] = 0.0f;
    __syncthreads();
    const int c = tid >> 4, a = tid & 15;
    float n2 = 0.0f;
    for (int it = 0; it < 3; ++it) {
        if (tid < 256) {
            const int r = tid >> 5, cc = tid & 31;
            const float l = logits[r][cc];
            float mx = l;
            #pragma unroll
            for (int m = 1; m < 32; m <<= 1) mx = fmaxf(mx, __shfl_xor(mx, m));
            const float e = __expf(l - mx);
            float sm = e;
            #pragma unroll
            for (int m = 1; m < 32; m <<= 1) sm += __shfl_xor(sm, m);
            route[r][cc] = e / sm;
        }
        __syncthreads();
        float pa = 0.0f;
        #pragma unroll
        for (int r = 0; r < 8; ++r) pa += route[r][c] * v[r][c][a];
        n2 = pa * pa;
        #pragma unroll
        for (int m = 1; m < 16; m <<= 1) n2 += __shfl_xor(n2, m);
        const float nrm = sqrtf(n2);
        const float av = pa * (nrm / (0.5f + n2));
        if (it < 2) {
            #pragma unroll
            for (int r = 0; r < 8; ++r) {
                float u = v[r][c][a] * av;
                #pragma unroll
                for (int m = 1; m < 16; m <<= 1) u += __shfl_xor(u, m);
                if (a == 0) logits[r][c] += u;
            }
        }
        __syncthreads();
    }
    if (a == 0) out[b * 32 + c] = n2 / (0.5f + n2);
}

// ---------------------------------------------------------------------------
static void launch_scan(const float* Z, const float* wf, const float* wb,
                        float* ob, int bt, unsigned int* hx32, int* fl,
                        hipStream_t stream)
{
    int base0 = 0;
    void* args[] = {(void*)&Z, (void*)&wf, (void*)&wb, (void*)&ob,
                    (void*)&bt, (void*)&hx32, (void*)&fl, (void*)&base0};
    if (hipLaunchCooperativeKernel((const void*)k_scan9, dim3(128), dim3(512),
                                   args, 0, stream) != hipSuccess) {
        // 128 blocks <= 256 CUs: all resident under plain launch too.
        k_scan9<<<dim3(128), 512, 0, stream>>>(Z, wf, wb, ob, bt, hx32, fl, 0);
    }
}

extern "C" void kernel_launch(void* const* d_in, const int* in_sizes, int n_in,
                              void* d_out, int out_size, void* d_ws, size_t ws_size,
                              hipStream_t stream) {
    (void)in_sizes; (void)n_in; (void)out_size; (void)ws_size;
    const int*   tokens  = (const int*)d_in[0];
    const float* emb     = (const float*)d_in[2];
    const float* w_ih_f0 = (const float*)d_in[3];
    const float* w_hh_f0 = (const float*)d_in[4];
    const float* b_f0    = (const float*)d_in[5];
    const float* w_ih_b0 = (const float*)d_in[6];
    const float* w_hh_b0 = (const float*)d_in[7];
    const float* b_b0    = (const float*)d_in[8];
    const float* w_ih_f1 = (const float*)d_in[9];
    const float* w_hh_f1 = (const float*)d_in[10];
    const float* b_f1    = (const float*)d_in[11];
    const float* w_ih_b1 = (const float*)d_in[12];
    const float* w_hh_b1 = (const float*)d_in[13];
    const float* b_b1    = (const float*)d_in[14];
    const float* ws1     = (const float*)d_in[15];
    const float* ws2     = (const float*)d_in[16];
    const float* caps    = (const float*)d_in[17];

    float* wsf  = (float*)d_ws;
    float* Wt   = wsf;                          //  4 * 262144
    float* Z    = Wt   + 4 * 262144;            //  8192*2048
    float* x1   = Z    + 16777216;              //  8192*512
    float* outp = x1   + 4194304;               //  8192*512
    float* hbar = outp + 4194304;               //  8192*128
    float* sent = hbar + 1048576;               //  128*8*512
    float* vote = sent + 524288;                //  128*8*512
    unsigned int* hx32 = (unsigned int*)(vote + 524288);  // 2*16*4096 u32
    int*   flags = (int*)(hx32 + 131072);       //  8192 ints
    float* out  = (float*)d_out;

    // 0. zero sync flags (every launch; replays don't re-poison)
    k_zero<<<dim3(32), 256, 0, stream>>>(flags, 8192);
    // 1. transpose recurrent weights
    k_transpose<<<dim3(32, 8, 4), dim3(32, 8), 0, stream>>>(w_hh_f0, w_hh_b0, w_hh_f1, w_hh_b1, Wt);
    // 2. layer-0 projection (bf16x3 MFMA, inline gather+split) -> Z
    k_mgemm<<<dim3(64, 16), 256, 0, stream>>>(
        emb, 300, tokens, w_ih_f0, w_ih_b0, 300, b_f0, b_b0, Z, 2048, 300, 320, 0);
    // 3. layer-0 scan -> x1 [t*128+b][512]
    launch_scan(Z, Wt, Wt + 262144, x1, 0, hx32, flags, stream);
    // 4. layer-1 projection (bf16x3 MFMA, inline split) -> Z
    k_mgemm<<<dim3(64, 16), 256, 0, stream>>>(
        x1, 512, (const int*)nullptr, w_ih_f1, w_ih_b1, 512, b_f1, b_b1, Z, 2048, 512, 512, 0);
    // 5. layer-1 scan -> outp [b*64+t][512]
    launch_scan(Z, Wt + 2 * 262144, Wt + 3 * 262144, outp, 1, hx32, flags + 4096, stream);
    // 6. hbar = tanh(outp @ ws1^T)  (MFMA + fused tanh)
    k_mgemm<<<dim3(64, 1), 256, 0, stream>>>(
        outp, 512, (const int*)nullptr, ws1, ws1, 512,
        (const float*)nullptr, (const float*)nullptr, hbar, 128, 512, 512, 1);
    // 7. attention + sent
    k_attnpool<<<dim3(128), 256, 0, stream>>>(hbar, outp, ws2, sent);
    // 8. votes
    k_gemm<<<dim3(1, 4, 8), 256, 0, stream>>>(
        sent, 4096, (const int*)nullptr, caps, (const float*)nullptr, 1 << 30, 512,
        (const float*)nullptr, (const float*)nullptr,
        vote, 4096, 512, 0, 0, 512LL, 262144LL, 512LL);
    // 9. routing
    k_routing<<<dim3(128), 512, 0, stream>>>(vote, out);
}